// Round 1
// baseline (1847.143 us; speedup 1.0000x reference)
//
#include <hip/hip_runtime.h>
#include <hip/hip_bf16.h>
#include <math.h>

#define NNODES 50000

// ============================ GEMM (fp32, tiled) ============================
#define BM 64
#define BN 64
#define BK 16

__global__ __launch_bounds__(256)
void gemm_f32(const float* __restrict__ A, const float* __restrict__ B,
              float* __restrict__ C, int M, int K, int Nc) {
    __shared__ float As[BK][BM + 1];   // +1 pad: avoid 16-way bank conflict on write
    __shared__ float Bs[BK][BN];

    int tid = threadIdx.x;
    int bm = blockIdx.y * BM;
    int bn = blockIdx.x * BN;
    int tx = tid & 15;         // 0..15 -> 4 output cols each
    int ty = tid >> 4;         // 0..15 -> 4 output rows each

    float acc[4][4] = {};

    for (int k0 = 0; k0 < K; k0 += BK) {
        // load A tile 64x16 (transposed into As[k][m])
        #pragma unroll
        for (int i = 0; i < 4; ++i) {
            int idx = tid + i * 256;
            int r = idx >> 4;        // 0..63
            int c = idx & 15;        // 0..15
            int gr = bm + r;
            As[c][r] = (gr < M) ? A[(size_t)gr * K + k0 + c] : 0.f;
        }
        // load B tile 16x64
        #pragma unroll
        for (int i = 0; i < 4; ++i) {
            int idx = tid + i * 256;
            int r = idx >> 6;        // 0..15
            int c = idx & 63;        // 0..63
            Bs[r][c] = B[(size_t)(k0 + r) * Nc + bn + c];
        }
        __syncthreads();

        #pragma unroll
        for (int k = 0; k < BK; ++k) {
            float a[4], b[4];
            #pragma unroll
            for (int i = 0; i < 4; ++i) a[i] = As[k][ty * 4 + i];
            #pragma unroll
            for (int j = 0; j < 4; ++j) b[j] = Bs[k][tx * 4 + j];
            #pragma unroll
            for (int i = 0; i < 4; ++i)
                #pragma unroll
                for (int j = 0; j < 4; ++j)
                    acc[i][j] += a[i] * b[j];
        }
        __syncthreads();
    }

    #pragma unroll
    for (int i = 0; i < 4; ++i) {
        int gr = bm + ty * 4 + i;
        if (gr < M) {
            #pragma unroll
            for (int j = 0; j < 4; ++j)
                C[(size_t)gr * Nc + bn + tx * 4 + j] = acc[i][j];
        }
    }
}

// ============================ CSR build =====================================
__global__ void deg_kernel(const int* __restrict__ ei, int E, int Nn,
                           int* __restrict__ deg) {
    int e = blockIdx.x * blockDim.x + threadIdx.x;
    int tot = E + Nn;
    if (e >= tot) return;
    int d = (e < E) ? ei[E + e] : (e - E);   // ei layout [2,E]: row1 = dst
    atomicAdd(&deg[d], 1);
}

__global__ __launch_bounds__(1024)
void scan_kernel(const int* __restrict__ deg, int* __restrict__ offs, int n) {
    __shared__ int sh[1024];
    __shared__ int carry_sh;
    int t = threadIdx.x;
    if (t == 0) carry_sh = 0;
    __syncthreads();
    for (int base = 0; base < n; base += 1024) {
        int i = base + t;
        int v = (i < n) ? deg[i] : 0;
        sh[t] = v;
        __syncthreads();
        for (int off = 1; off < 1024; off <<= 1) {
            int add = (t >= off) ? sh[t - off] : 0;
            __syncthreads();
            sh[t] += add;
            __syncthreads();
        }
        int carry = carry_sh;
        if (i < n) offs[i + 1] = carry + sh[t];
        __syncthreads();
        if (t == 1023) carry_sh = carry + sh[1023];
        __syncthreads();
    }
    if (t == 0) offs[0] = 0;
}

__global__ void copy_int_kernel(const int* __restrict__ src, int* __restrict__ dst, int n) {
    int i = blockIdx.x * blockDim.x + threadIdx.x;
    if (i < n) dst[i] = src[i];
}

__global__ void scatter_kernel(const int* __restrict__ ei, int E, int Nn,
                               int* __restrict__ cursor, int* __restrict__ csr_src) {
    int e = blockIdx.x * blockDim.x + threadIdx.x;
    int tot = E + Nn;
    if (e >= tot) return;
    int s, d;
    if (e < E) { s = ei[e]; d = ei[E + e]; }
    else       { s = d = e - E; }
    int pos = atomicAdd(&cursor[d], 1);
    csr_src[pos] = s;
}

// ===================== per-node attention scores ============================
template<int H>
__global__ __launch_bounds__(256)
void score_kernel(const float* __restrict__ hbuf, const float* __restrict__ a_src,
                  const float* __restrict__ a_dst, float* __restrict__ s_src,
                  float* __restrict__ s_dst, int Nn) {
    int wid = (blockIdx.x * blockDim.x + threadIdx.x) >> 6;
    int lane = threadIdx.x & 63;
    if (wid >= Nn) return;
    const float* hrow = hbuf + (size_t)wid * (H * 64);
    #pragma unroll
    for (int h = 0; h < H; ++h) {
        float v = hrow[h * 64 + lane];
        float ps = v * a_src[h * 64 + lane];
        float pd = v * a_dst[h * 64 + lane];
        #pragma unroll
        for (int off = 32; off; off >>= 1) {
            ps += __shfl_xor(ps, off);
            pd += __shfl_xor(pd, off);
        }
        if (lane == 0) {
            s_src[wid * H + h] = ps;
            s_dst[wid * H + h] = pd;
        }
    }
}

// ===================== segment softmax + aggregation ========================
// one wave per destination node; lane = output channel
template<int H, bool MEAN>
__global__ __launch_bounds__(256)
void agg_kernel(const float* __restrict__ hbuf, const float* __restrict__ s_src,
                const float* __restrict__ s_dst, const int* __restrict__ offs,
                const int* __restrict__ csr_src, const float* __restrict__ bias,
                float* __restrict__ out, int Nn) {
    int wid = (blockIdx.x * blockDim.x + threadIdx.x) >> 6;
    int lane = threadIdx.x & 63;
    if (wid >= Nn) return;
    int n = wid;
    int beg = offs[n], end = offs[n + 1];

    float mean_acc = 0.f;
    #pragma unroll
    for (int h = 0; h < H; ++h) {
        float sdst = s_dst[n * H + h];
        // pass 1: max over edge scores (lane-parallel)
        float mx = -INFINITY;
        for (int i = beg + lane; i < end; i += 64) {
            int s = csr_src[i];
            float sc = s_src[s * H + h] + sdst;
            sc = sc > 0.f ? sc : 0.2f * sc;
            mx = fmaxf(mx, sc);
        }
        #pragma unroll
        for (int off = 32; off; off >>= 1) mx = fmaxf(mx, __shfl_xor(mx, off));
        // pass 2: wave-uniform loop over edges; lane = channel
        float acc = 0.f, denom = 0.f;
        for (int i = beg; i < end; ++i) {
            int s = csr_src[i];
            float sc = s_src[s * H + h] + sdst;
            sc = sc > 0.f ? sc : 0.2f * sc;
            float w = expf(sc - mx);
            denom += w;
            acc += w * hbuf[((size_t)s * H + h) * 64 + lane];
        }
        float val = acc / (denom + 1e-16f);
        if (!MEAN) {
            val += bias[h * 64 + lane];
            val = val > 0.f ? val : expm1f(val);   // ELU
            out[(size_t)n * (H * 64) + h * 64 + lane] = val;
        } else {
            mean_acc += val;
        }
    }
    if (MEAN) {
        out[(size_t)n * 64 + lane] = mean_acc / (float)H + bias[lane];
    }
}

// ============================ launch ========================================
extern "C" void kernel_launch(void* const* d_in, const int* in_sizes, int n_in,
                              void* d_out, int out_size, void* d_ws, size_t ws_size,
                              hipStream_t stream) {
    const float* x     = (const float*)d_in[0];
    const int*   ei    = (const int*)d_in[1];
    const float* W1    = (const float*)d_in[2];
    const float* a1s   = (const float*)d_in[3];
    const float* a1d   = (const float*)d_in[4];
    const float* b1    = (const float*)d_in[5];
    const float* W2    = (const float*)d_in[6];
    const float* a2s   = (const float*)d_in[7];
    const float* a2d   = (const float*)d_in[8];
    const float* b2    = (const float*)d_in[9];
    const float* W3    = (const float*)d_in[10];
    const float* a3s   = (const float*)d_in[11];
    const float* a3d   = (const float*)d_in[12];
    const float* b3    = (const float*)d_in[13];
    float* out = (float*)d_out;

    const int Nn = NNODES;
    const int E  = in_sizes[1] / 2;       // [2, E]
    const int Etot = E + Nn;

    // -------- workspace carve (256B aligned) --------
    char* p = (char*)d_ws;
    auto carve = [&](size_t bytes) {
        char* r = p;
        p += (bytes + 255) & ~(size_t)255;
        return (void*)r;
    };
    float* h_buf  = (float*)carve((size_t)Nn * 384 * 4);
    float* x1     = (float*)carve((size_t)Nn * 256 * 4);
    float* x2     = (float*)carve((size_t)Nn * 256 * 4);
    float* ssrc   = (float*)carve((size_t)Nn * 6 * 4);
    float* sdst   = (float*)carve((size_t)Nn * 6 * 4);
    int*   deg    = (int*)carve((size_t)Nn * 4);
    int*   offs   = (int*)carve((size_t)(Nn + 1) * 4);
    int*   cursor = (int*)carve((size_t)Nn * 4);
    int*   csr    = (int*)carve((size_t)Etot * 4);

    // -------- CSR build (edges shared by all 3 layers) --------
    hipMemsetAsync(deg, 0, (size_t)Nn * 4, stream);
    {
        int nb = (Etot + 255) / 256;
        deg_kernel<<<nb, 256, 0, stream>>>(ei, E, Nn, deg);
        scan_kernel<<<1, 1024, 0, stream>>>(deg, offs, Nn);
        copy_int_kernel<<<(Nn + 255) / 256, 256, 0, stream>>>(offs, cursor, Nn);
        scatter_kernel<<<nb, 256, 0, stream>>>(ei, E, Nn, cursor, csr);
    }

    const int node_blocks = (Nn + 3) / 4;   // 4 waves (nodes) per 256-thread block

    // -------- layer 1: [50000,128]@[128,256], H=4, concat+ELU --------
    {
        dim3 g(256 / BN, (Nn + BM - 1) / BM);
        gemm_f32<<<g, 256, 0, stream>>>(x, W1, h_buf, Nn, 128, 256);
        score_kernel<4><<<node_blocks, 256, 0, stream>>>(h_buf, a1s, a1d, ssrc, sdst, Nn);
        agg_kernel<4, false><<<node_blocks, 256, 0, stream>>>(h_buf, ssrc, sdst, offs, csr, b1, x1, Nn);
    }
    // -------- layer 2: [50000,256]@[256,256], H=4, concat+ELU --------
    {
        dim3 g(256 / BN, (Nn + BM - 1) / BM);
        gemm_f32<<<g, 256, 0, stream>>>(x1, W2, h_buf, Nn, 256, 256);
        score_kernel<4><<<node_blocks, 256, 0, stream>>>(h_buf, a2s, a2d, ssrc, sdst, Nn);
        agg_kernel<4, false><<<node_blocks, 256, 0, stream>>>(h_buf, ssrc, sdst, offs, csr, b2, x2, Nn);
    }
    // -------- layer 3: [50000,256]@[256,384], H=6, mean --------
    {
        dim3 g(384 / BN, (Nn + BM - 1) / BM);
        gemm_f32<<<g, 256, 0, stream>>>(x2, W3, h_buf, Nn, 256, 384);
        score_kernel<6><<<node_blocks, 256, 0, stream>>>(h_buf, a3s, a3d, ssrc, sdst, Nn);
        agg_kernel<6, true><<<node_blocks, 256, 0, stream>>>(h_buf, ssrc, sdst, offs, csr, b3, out, Nn);
    }
}

// Round 2
// 1106.362 us; speedup vs baseline: 1.6696x; 1.6696x over previous
//
#include <hip/hip_runtime.h>
#include <hip/hip_bf16.h>
#include <math.h>

#define NNODES 50000

// ============================ GEMM (fp32, tiled) ============================
#define BM 64
#define BN 64
#define BK 16

__global__ __launch_bounds__(256)
void gemm_f32(const float* __restrict__ A, const float* __restrict__ B,
              float* __restrict__ C, int M, int K, int Nc) {
    __shared__ float As[BK][BM + 1];
    __shared__ float Bs[BK][BN];

    int tid = threadIdx.x;
    int bm = blockIdx.y * BM;
    int bn = blockIdx.x * BN;
    int tx = tid & 15;
    int ty = tid >> 4;

    float acc[4][4] = {};

    for (int k0 = 0; k0 < K; k0 += BK) {
        #pragma unroll
        for (int i = 0; i < 4; ++i) {
            int idx = tid + i * 256;
            int r = idx >> 4;
            int c = idx & 15;
            int gr = bm + r;
            As[c][r] = (gr < M) ? A[(size_t)gr * K + k0 + c] : 0.f;
        }
        #pragma unroll
        for (int i = 0; i < 4; ++i) {
            int idx = tid + i * 256;
            int r = idx >> 6;
            int c = idx & 63;
            Bs[r][c] = B[(size_t)(k0 + r) * Nc + bn + c];
        }
        __syncthreads();

        #pragma unroll
        for (int k = 0; k < BK; ++k) {
            float a[4], b[4];
            #pragma unroll
            for (int i = 0; i < 4; ++i) a[i] = As[k][ty * 4 + i];
            #pragma unroll
            for (int j = 0; j < 4; ++j) b[j] = Bs[k][tx * 4 + j];
            #pragma unroll
            for (int i = 0; i < 4; ++i)
                #pragma unroll
                for (int j = 0; j < 4; ++j)
                    acc[i][j] += a[i] * b[j];
        }
        __syncthreads();
    }

    #pragma unroll
    for (int i = 0; i < 4; ++i) {
        int gr = bm + ty * 4 + i;
        if (gr < M) {
            #pragma unroll
            for (int j = 0; j < 4; ++j)
                C[(size_t)gr * Nc + bn + tx * 4 + j] = acc[i][j];
        }
    }
}

// ============================ CSR build =====================================
__global__ void deg_kernel(const int* __restrict__ ei, int E, int Nn,
                           int* __restrict__ deg) {
    int e = blockIdx.x * blockDim.x + threadIdx.x;
    int tot = E + Nn;
    if (e >= tot) return;
    int d = (e < E) ? ei[E + e] : (e - E);
    atomicAdd(&deg[d], 1);
}

__global__ __launch_bounds__(1024)
void scan_kernel(const int* __restrict__ deg, int* __restrict__ offs, int n) {
    __shared__ int sh[1024];
    __shared__ int carry_sh;
    int t = threadIdx.x;
    if (t == 0) carry_sh = 0;
    __syncthreads();
    for (int base = 0; base < n; base += 1024) {
        int i = base + t;
        int v = (i < n) ? deg[i] : 0;
        sh[t] = v;
        __syncthreads();
        for (int off = 1; off < 1024; off <<= 1) {
            int add = (t >= off) ? sh[t - off] : 0;
            __syncthreads();
            sh[t] += add;
            __syncthreads();
        }
        int carry = carry_sh;
        if (i < n) offs[i + 1] = carry + sh[t];
        __syncthreads();
        if (t == 1023) carry_sh = carry + sh[1023];
        __syncthreads();
    }
    if (t == 0) offs[0] = 0;
}

__global__ void copy_int_kernel(const int* __restrict__ src, int* __restrict__ dst, int n) {
    int i = blockIdx.x * blockDim.x + threadIdx.x;
    if (i < n) dst[i] = src[i];
}

__global__ void scatter_kernel(const int* __restrict__ ei, int E, int Nn,
                               int* __restrict__ cursor, int* __restrict__ csr_src) {
    int e = blockIdx.x * blockDim.x + threadIdx.x;
    int tot = E + Nn;
    if (e >= tot) return;
    int s, d;
    if (e < E) { s = ei[e]; d = ei[E + e]; }
    else       { s = d = e - E; }
    int pos = atomicAdd(&cursor[d], 1);
    csr_src[pos] = s;
}

// ===================== per-node attention scores ============================
template<int H>
__global__ __launch_bounds__(256)
void score_kernel(const float* __restrict__ hbuf, const float* __restrict__ a_src,
                  const float* __restrict__ a_dst, float* __restrict__ s_src,
                  float* __restrict__ s_dst, int Nn) {
    int wid = (blockIdx.x * blockDim.x + threadIdx.x) >> 6;
    int lane = threadIdx.x & 63;
    if (wid >= Nn) return;
    const float* hrow = hbuf + (size_t)wid * (H * 64);
    #pragma unroll
    for (int h = 0; h < H; ++h) {
        float v = hrow[h * 64 + lane];
        float ps = v * a_src[h * 64 + lane];
        float pd = v * a_dst[h * 64 + lane];
        #pragma unroll
        for (int off = 32; off; off >>= 1) {
            ps += __shfl_xor(ps, off);
            pd += __shfl_xor(pd, off);
        }
        if (lane == 0) {
            s_src[wid * H + h] = ps;
            s_dst[wid * H + h] = pd;
        }
    }
}

// ============ score -> max -> edge weights + recip denominator ==============
// wave per node, lanes strided over incoming edges.
// leaky_relu is monotone: max_e leaky(ssrc_e + sdst) = leaky(max_e ssrc_e + sdst)
template<int H>
__global__ __launch_bounds__(256)
void smw_kernel(const float* __restrict__ ssrc, const float* __restrict__ sdst,
                const int* __restrict__ offs, const int* __restrict__ csr,
                float* __restrict__ wbuf, float* __restrict__ rden, int Nn) {
    int wid = (blockIdx.x * blockDim.x + threadIdx.x) >> 6;
    int lane = threadIdx.x & 63;
    if (wid >= Nn) return;
    int beg = offs[wid], end = offs[wid + 1];
    float sd[H], mx[H], den[H];
    #pragma unroll
    for (int h = 0; h < H; ++h) {
        sd[h] = sdst[wid * H + h];
        mx[h] = -INFINITY;
        den[h] = 0.f;
    }
    for (int i = beg + lane; i < end; i += 64) {
        int s = csr[i];
        #pragma unroll
        for (int h = 0; h < H; ++h) mx[h] = fmaxf(mx[h], ssrc[s * H + h]);
    }
    #pragma unroll
    for (int h = 0; h < H; ++h) {
        #pragma unroll
        for (int off = 32; off; off >>= 1) mx[h] = fmaxf(mx[h], __shfl_xor(mx[h], off));
        float t = mx[h] + sd[h];
        mx[h] = t > 0.f ? t : 0.2f * t;           // = max of leaky'd scores
    }
    for (int i = beg + lane; i < end; i += 64) {
        int s = csr[i];
        #pragma unroll
        for (int h = 0; h < H; ++h) {
            float sc = ssrc[s * H + h] + sd[h];
            sc = sc > 0.f ? sc : 0.2f * sc;
            float w = __expf(sc - mx[h]);
            wbuf[(size_t)i * H + h] = w;
            den[h] += w;
        }
    }
    #pragma unroll
    for (int h = 0; h < H; ++h) {
        #pragma unroll
        for (int off = 32; off; off >>= 1) den[h] += __shfl_xor(den[h], off);
    }
    if (lane == 0) {
        #pragma unroll
        for (int h = 0; h < H; ++h) rden[wid * H + h] = 1.f / (den[h] + 1e-16f);
    }
}

// ===================== weighted aggregation (pure fma) ======================
// wave per node, lane = channel; all H heads per edge-row visit.
template<int H, bool MEAN>
__global__ __launch_bounds__(256)
void agg_kernel(const float* __restrict__ hbuf, const float* __restrict__ wbuf,
                const float* __restrict__ rden, const int* __restrict__ offs,
                const int* __restrict__ csr, const float* __restrict__ bias,
                float* __restrict__ out, int Nn) {
    int wid = (blockIdx.x * blockDim.x + threadIdx.x) >> 6;
    int lane = threadIdx.x & 63;
    if (wid >= Nn) return;
    int beg = offs[wid], end = offs[wid + 1];

    float acc[H] = {};
    int i = beg;
    for (; i + 2 <= end; i += 2) {
        int s0 = csr[i], s1 = csr[i + 1];
        const float* r0 = hbuf + (size_t)s0 * (H * 64) + lane;
        const float* r1 = hbuf + (size_t)s1 * (H * 64) + lane;
        float w0[H], w1[H], v0[H], v1[H];
        #pragma unroll
        for (int h = 0; h < H; ++h) { v0[h] = r0[h * 64]; w0[h] = wbuf[(size_t)i * H + h]; }
        #pragma unroll
        for (int h = 0; h < H; ++h) { v1[h] = r1[h * 64]; w1[h] = wbuf[(size_t)(i + 1) * H + h]; }
        #pragma unroll
        for (int h = 0; h < H; ++h) acc[h] += w0[h] * v0[h] + w1[h] * v1[h];
    }
    if (i < end) {
        int s = csr[i];
        const float* r = hbuf + (size_t)s * (H * 64) + lane;
        #pragma unroll
        for (int h = 0; h < H; ++h) acc[h] += wbuf[(size_t)i * H + h] * r[h * 64];
    }

    if (!MEAN) {
        #pragma unroll
        for (int h = 0; h < H; ++h) {
            float val = acc[h] * rden[wid * H + h] + bias[h * 64 + lane];
            val = val > 0.f ? val : expm1f(val);   // ELU
            out[(size_t)wid * (H * 64) + h * 64 + lane] = val;
        }
    } else {
        float m = 0.f;
        #pragma unroll
        for (int h = 0; h < H; ++h) m += acc[h] * rden[wid * H + h];
        out[(size_t)wid * 64 + lane] = m * (1.f / (float)H) + bias[lane];
    }
}

// ============================ launch ========================================
extern "C" void kernel_launch(void* const* d_in, const int* in_sizes, int n_in,
                              void* d_out, int out_size, void* d_ws, size_t ws_size,
                              hipStream_t stream) {
    const float* x     = (const float*)d_in[0];
    const int*   ei    = (const int*)d_in[1];
    const float* W1    = (const float*)d_in[2];
    const float* a1s   = (const float*)d_in[3];
    const float* a1d   = (const float*)d_in[4];
    const float* b1    = (const float*)d_in[5];
    const float* W2    = (const float*)d_in[6];
    const float* a2s   = (const float*)d_in[7];
    const float* a2d   = (const float*)d_in[8];
    const float* b2    = (const float*)d_in[9];
    const float* W3    = (const float*)d_in[10];
    const float* a3s   = (const float*)d_in[11];
    const float* a3d   = (const float*)d_in[12];
    const float* b3    = (const float*)d_in[13];
    float* out = (float*)d_out;

    const int Nn = NNODES;
    const int E  = in_sizes[1] / 2;
    const int Etot = E + Nn;

    char* p = (char*)d_ws;
    auto carve = [&](size_t bytes) {
        char* r = p;
        p += (bytes + 255) & ~(size_t)255;
        return (void*)r;
    };
    float* h_buf  = (float*)carve((size_t)Nn * 384 * 4);
    float* x1     = (float*)carve((size_t)Nn * 256 * 4);
    float* x2     = x1;                              // alias: x1 dead before x2 written
    float* ssrc   = (float*)carve((size_t)Nn * 6 * 4);
    float* sdst   = (float*)carve((size_t)Nn * 6 * 4);
    float* wbuf   = (float*)carve((size_t)Etot * 6 * 4);
    float* rden   = (float*)carve((size_t)Nn * 6 * 4);
    int*   deg    = (int*)carve((size_t)Nn * 4);
    int*   offs   = (int*)carve((size_t)(Nn + 1) * 4);
    int*   cursor = (int*)carve((size_t)Nn * 4);
    int*   csr    = (int*)carve((size_t)Etot * 4);

    // -------- CSR build (edges shared by all 3 layers) --------
    hipMemsetAsync(deg, 0, (size_t)Nn * 4, stream);
    {
        int nb = (Etot + 255) / 256;
        deg_kernel<<<nb, 256, 0, stream>>>(ei, E, Nn, deg);
        scan_kernel<<<1, 1024, 0, stream>>>(deg, offs, Nn);
        copy_int_kernel<<<(Nn + 255) / 256, 256, 0, stream>>>(offs, cursor, Nn);
        scatter_kernel<<<nb, 256, 0, stream>>>(ei, E, Nn, cursor, csr);
    }

    const int node_blocks = (Nn + 3) / 4;

    // -------- layer 1 --------
    {
        dim3 g(256 / BN, (Nn + BM - 1) / BM);
        gemm_f32<<<g, 256, 0, stream>>>(x, W1, h_buf, Nn, 128, 256);
        score_kernel<4><<<node_blocks, 256, 0, stream>>>(h_buf, a1s, a1d, ssrc, sdst, Nn);
        smw_kernel<4><<<node_blocks, 256, 0, stream>>>(ssrc, sdst, offs, csr, wbuf, rden, Nn);
        agg_kernel<4, false><<<node_blocks, 256, 0, stream>>>(h_buf, wbuf, rden, offs, csr, b1, x1, Nn);
    }
    // -------- layer 2 --------
    {
        dim3 g(256 / BN, (Nn + BM - 1) / BM);
        gemm_f32<<<g, 256, 0, stream>>>(x1, W2, h_buf, Nn, 256, 256);
        score_kernel<4><<<node_blocks, 256, 0, stream>>>(h_buf, a2s, a2d, ssrc, sdst, Nn);
        smw_kernel<4><<<node_blocks, 256, 0, stream>>>(ssrc, sdst, offs, csr, wbuf, rden, Nn);
        agg_kernel<4, false><<<node_blocks, 256, 0, stream>>>(h_buf, wbuf, rden, offs, csr, b2, x2, Nn);
    }
    // -------- layer 3 --------
    {
        dim3 g(384 / BN, (Nn + BM - 1) / BM);
        gemm_f32<<<g, 256, 0, stream>>>(x2, W3, h_buf, Nn, 256, 384);
        score_kernel<6><<<node_blocks, 256, 0, stream>>>(h_buf, a3s, a3d, ssrc, sdst, Nn);
        smw_kernel<6><<<node_blocks, 256, 0, stream>>>(ssrc, sdst, offs, csr, wbuf, rden, Nn);
        agg_kernel<6, true><<<node_blocks, 256, 0, stream>>>(h_buf, wbuf, rden, offs, csr, b3, out, Nn);
    }
}

// Round 3
// 981.299 us; speedup vs baseline: 1.8823x; 1.1274x over previous
//
#include <hip/hip_runtime.h>
#include <hip/hip_bf16.h>
#include <math.h>

#define NNODES 50000

typedef __attribute__((ext_vector_type(8))) short short8v;
typedef __attribute__((ext_vector_type(4))) float f32x4;
typedef unsigned short ushort_t;

// ---------------- bf16 split helpers ----------------
__device__ inline ushort_t f2bf_bits(float v) {
    union { __hip_bfloat16 b; ushort_t u; } c;
    c.b = __float2bfloat16(v);
    return c.u;
}
__device__ inline float bfbits2f(ushort_t u) {
    union { __hip_bfloat16 b; ushort_t u; } c;
    c.u = u;
    return __bfloat162float(c.b);
}

// split fp32 -> (hi, lo) bf16 pair, vectorized x4
__global__ __launch_bounds__(256)
void split_kernel(const float4* __restrict__ in, ushort4* __restrict__ hi,
                  ushort4* __restrict__ lo, int n4) {
    int i = blockIdx.x * blockDim.x + threadIdx.x;
    if (i >= n4) return;
    float4 v = in[i];
    ushort4 h, l;
    h.x = f2bf_bits(v.x); l.x = f2bf_bits(v.x - bfbits2f(h.x));
    h.y = f2bf_bits(v.y); l.y = f2bf_bits(v.y - bfbits2f(h.y));
    h.z = f2bf_bits(v.z); l.z = f2bf_bits(v.z - bfbits2f(h.z));
    h.w = f2bf_bits(v.w); l.w = f2bf_bits(v.w - bfbits2f(h.w));
    hi[i] = h; lo[i] = l;
}

// W [K][N] fp32 -> WT_hi/WT_lo [N][K] bf16
__global__ __launch_bounds__(256)
void wprep_kernel(const float* __restrict__ W, ushort_t* __restrict__ hiT,
                  ushort_t* __restrict__ loT, int K, int N) {
    int idx = blockIdx.x * blockDim.x + threadIdx.x;
    if (idx >= K * N) return;
    int k = idx / N, n = idx - k * N;
    float v = W[idx];
    ushort_t hb = f2bf_bits(v);
    hiT[(size_t)n * K + k] = hb;
    loT[(size_t)n * K + k] = f2bf_bits(v - bfbits2f(hb));
}

// ================= split-bf16 3-pass MFMA GEMM =================
// C[M][N] = A[M][K] * B[K][N];  A given as hi/lo bf16 [M][K],
// B given as hi/lo bf16 transposed [N][K].
// Block: 256 thr = 4 waves (2x2), BM=128, BN=64, BK=32; wave tile 64x32.
#define GTILE_LDA 40   // padded LDS row stride in bf16 elems (80 B)

__global__ __launch_bounds__(256)
void gemm_split_bf16(const ushort_t* __restrict__ Ahi, const ushort_t* __restrict__ Alo,
                     const ushort_t* __restrict__ Bhi, const ushort_t* __restrict__ Blo,
                     float* __restrict__ C, int M, int K, int N) {
    __shared__ short Ash_hi[128 * GTILE_LDA];
    __shared__ short Ash_lo[128 * GTILE_LDA];
    __shared__ short Bsh_hi[64 * GTILE_LDA];
    __shared__ short Bsh_lo[64 * GTILE_LDA];

    int tid = threadIdx.x;
    int lane = tid & 63;
    int wid = tid >> 6;
    int wm = wid >> 1, wn = wid & 1;
    int bm = blockIdx.y * 128;
    int bn = blockIdx.x * 64;
    int r15 = lane & 15;
    int kh = (lane >> 4) * 8;      // k-offset of this lane's 8 contiguous elems

    f32x4 acc[4][2] = {};

    for (int k0 = 0; k0 < K; k0 += 32) {
        // ---- stage A (128x32 hi+lo): 512 chunks of 16B, 2 per thread ----
        #pragma unroll
        for (int j = 0; j < 2; ++j) {
            int c = tid + j * 256;
            int row = c >> 2;
            int kc = c & 3;
            int gr = bm + row;
            short8v vh = {}, vl = {};
            if (gr < M) {
                vh = *(const short8v*)&Ahi[(size_t)gr * K + k0 + kc * 8];
                vl = *(const short8v*)&Alo[(size_t)gr * K + k0 + kc * 8];
            }
            *(short8v*)&Ash_hi[row * GTILE_LDA + kc * 8] = vh;
            *(short8v*)&Ash_lo[row * GTILE_LDA + kc * 8] = vl;
        }
        // ---- stage B (64x32 hi+lo): 256 chunks, 1 per thread ----
        {
            int row = tid >> 2;
            int kc = tid & 3;
            *(short8v*)&Bsh_hi[row * GTILE_LDA + kc * 8] =
                *(const short8v*)&Bhi[(size_t)(bn + row) * K + k0 + kc * 8];
            *(short8v*)&Bsh_lo[row * GTILE_LDA + kc * 8] =
                *(const short8v*)&Blo[(size_t)(bn + row) * K + k0 + kc * 8];
        }
        __syncthreads();

        short8v ah[4], al[4], bh[2], bl[2];
        #pragma unroll
        for (int mi = 0; mi < 4; ++mi) {
            int r = wm * 64 + mi * 16 + r15;
            ah[mi] = *(const short8v*)&Ash_hi[r * GTILE_LDA + kh];
            al[mi] = *(const short8v*)&Ash_lo[r * GTILE_LDA + kh];
        }
        #pragma unroll
        for (int nj = 0; nj < 2; ++nj) {
            int r = wn * 32 + nj * 16 + r15;
            bh[nj] = *(const short8v*)&Bsh_hi[r * GTILE_LDA + kh];
            bl[nj] = *(const short8v*)&Bsh_lo[r * GTILE_LDA + kh];
        }
        #pragma unroll
        for (int mi = 0; mi < 4; ++mi)
            #pragma unroll
            for (int nj = 0; nj < 2; ++nj) {
                acc[mi][nj] = __builtin_amdgcn_mfma_f32_16x16x32_bf16(ah[mi], bh[nj], acc[mi][nj], 0, 0, 0);
                acc[mi][nj] = __builtin_amdgcn_mfma_f32_16x16x32_bf16(ah[mi], bl[nj], acc[mi][nj], 0, 0, 0);
                acc[mi][nj] = __builtin_amdgcn_mfma_f32_16x16x32_bf16(al[mi], bh[nj], acc[mi][nj], 0, 0, 0);
            }
        __syncthreads();
    }

    // epilogue: C/D layout col=lane&15, row=(lane>>4)*4+reg
    #pragma unroll
    for (int mi = 0; mi < 4; ++mi) {
        #pragma unroll
        for (int r = 0; r < 4; ++r) {
            int grow = bm + wm * 64 + mi * 16 + (lane >> 4) * 4 + r;
            if (grow < M) {
                #pragma unroll
                for (int nj = 0; nj < 2; ++nj)
                    C[(size_t)grow * N + bn + wn * 32 + nj * 16 + r15] = acc[mi][nj][r];
            }
        }
    }
}

// ============================ CSR build =====================================
__global__ void deg_kernel(const int* __restrict__ ei, int E, int Nn,
                           int* __restrict__ deg) {
    int e = blockIdx.x * blockDim.x + threadIdx.x;
    int tot = E + Nn;
    if (e >= tot) return;
    int d = (e < E) ? ei[E + e] : (e - E);
    atomicAdd(&deg[d], 1);
}

__global__ __launch_bounds__(1024)
void scan_kernel(const int* __restrict__ deg, int* __restrict__ offs, int n) {
    __shared__ int sh[1024];
    __shared__ int carry_sh;
    int t = threadIdx.x;
    if (t == 0) carry_sh = 0;
    __syncthreads();
    for (int base = 0; base < n; base += 1024) {
        int i = base + t;
        int v = (i < n) ? deg[i] : 0;
        sh[t] = v;
        __syncthreads();
        for (int off = 1; off < 1024; off <<= 1) {
            int add = (t >= off) ? sh[t - off] : 0;
            __syncthreads();
            sh[t] += add;
            __syncthreads();
        }
        int carry = carry_sh;
        if (i < n) offs[i + 1] = carry + sh[t];
        __syncthreads();
        if (t == 1023) carry_sh = carry + sh[1023];
        __syncthreads();
    }
    if (t == 0) offs[0] = 0;
}

__global__ void copy_int_kernel(const int* __restrict__ src, int* __restrict__ dst, int n) {
    int i = blockIdx.x * blockDim.x + threadIdx.x;
    if (i < n) dst[i] = src[i];
}

__global__ void scatter_kernel(const int* __restrict__ ei, int E, int Nn,
                               int* __restrict__ cursor, int* __restrict__ csr_src) {
    int e = blockIdx.x * blockDim.x + threadIdx.x;
    int tot = E + Nn;
    if (e >= tot) return;
    int s, d;
    if (e < E) { s = ei[e]; d = ei[E + e]; }
    else       { s = d = e - E; }
    int pos = atomicAdd(&cursor[d], 1);
    csr_src[pos] = s;
}

// ===================== per-node attention scores ============================
template<int H>
__global__ __launch_bounds__(256)
void score_kernel(const float* __restrict__ hbuf, const float* __restrict__ a_src,
                  const float* __restrict__ a_dst, float* __restrict__ s_src,
                  float* __restrict__ s_dst, int Nn) {
    int wid = (blockIdx.x * blockDim.x + threadIdx.x) >> 6;
    int lane = threadIdx.x & 63;
    if (wid >= Nn) return;
    const float* hrow = hbuf + (size_t)wid * (H * 64);
    #pragma unroll
    for (int h = 0; h < H; ++h) {
        float v = hrow[h * 64 + lane];
        float ps = v * a_src[h * 64 + lane];
        float pd = v * a_dst[h * 64 + lane];
        #pragma unroll
        for (int off = 32; off; off >>= 1) {
            ps += __shfl_xor(ps, off);
            pd += __shfl_xor(pd, off);
        }
        if (lane == 0) {
            s_src[wid * H + h] = ps;
            s_dst[wid * H + h] = pd;
        }
    }
}

// ============ score -> max -> edge weights + recip denominator ==============
template<int H>
__global__ __launch_bounds__(256)
void smw_kernel(const float* __restrict__ ssrc, const float* __restrict__ sdst,
                const int* __restrict__ offs, const int* __restrict__ csr,
                float* __restrict__ wbuf, float* __restrict__ rden, int Nn) {
    int wid = (blockIdx.x * blockDim.x + threadIdx.x) >> 6;
    int lane = threadIdx.x & 63;
    if (wid >= Nn) return;
    int beg = offs[wid], end = offs[wid + 1];
    float sd[H], mx[H], den[H];
    #pragma unroll
    for (int h = 0; h < H; ++h) {
        sd[h] = sdst[wid * H + h];
        mx[h] = -INFINITY;
        den[h] = 0.f;
    }
    for (int i = beg + lane; i < end; i += 64) {
        int s = csr[i];
        #pragma unroll
        for (int h = 0; h < H; ++h) mx[h] = fmaxf(mx[h], ssrc[s * H + h]);
    }
    #pragma unroll
    for (int h = 0; h < H; ++h) {
        #pragma unroll
        for (int off = 32; off; off >>= 1) mx[h] = fmaxf(mx[h], __shfl_xor(mx[h], off));
        float t = mx[h] + sd[h];
        mx[h] = t > 0.f ? t : 0.2f * t;
    }
    for (int i = beg + lane; i < end; i += 64) {
        int s = csr[i];
        #pragma unroll
        for (int h = 0; h < H; ++h) {
            float sc = ssrc[s * H + h] + sd[h];
            sc = sc > 0.f ? sc : 0.2f * sc;
            float w = __expf(sc - mx[h]);
            wbuf[(size_t)i * H + h] = w;
            den[h] += w;
        }
    }
    #pragma unroll
    for (int h = 0; h < H; ++h) {
        #pragma unroll
        for (int off = 32; off; off >>= 1) den[h] += __shfl_xor(den[h], off);
    }
    if (lane == 0) {
        #pragma unroll
        for (int h = 0; h < H; ++h) rden[wid * H + h] = 1.f / (den[h] + 1e-16f);
    }
}

// ===================== weighted aggregation (pure fma) ======================
// wave per node, lane = channel; 4-edge unroll for MLP.
template<int H, bool MEAN>
__global__ __launch_bounds__(256)
void agg_kernel(const float* __restrict__ hbuf, const float* __restrict__ wbuf,
                const float* __restrict__ rden, const int* __restrict__ offs,
                const int* __restrict__ csr, const float* __restrict__ bias,
                float* __restrict__ outf, ushort_t* __restrict__ ohi,
                ushort_t* __restrict__ olo, int Nn) {
    int wid = (blockIdx.x * blockDim.x + threadIdx.x) >> 6;
    int lane = threadIdx.x & 63;
    if (wid >= Nn) return;
    int beg = offs[wid], end = offs[wid + 1];

    float acc0[H] = {}, acc1[H] = {};
    int i = beg;
    for (; i + 4 <= end; i += 4) {
        int s0 = csr[i], s1 = csr[i + 1], s2 = csr[i + 2], s3 = csr[i + 3];
        const float* r0 = hbuf + (size_t)s0 * (H * 64) + lane;
        const float* r1 = hbuf + (size_t)s1 * (H * 64) + lane;
        const float* r2 = hbuf + (size_t)s2 * (H * 64) + lane;
        const float* r3 = hbuf + (size_t)s3 * (H * 64) + lane;
        float w0[H], w1[H], w2[H], w3[H];
        if constexpr (H == 4) {
            float4 a = *(const float4*)&wbuf[(size_t)i * 4];
            float4 b = *(const float4*)&wbuf[(size_t)(i + 1) * 4];
            float4 c = *(const float4*)&wbuf[(size_t)(i + 2) * 4];
            float4 d = *(const float4*)&wbuf[(size_t)(i + 3) * 4];
            w0[0]=a.x; w0[1]=a.y; w0[2]=a.z; w0[3]=a.w;
            w1[0]=b.x; w1[1]=b.y; w1[2]=b.z; w1[3]=b.w;
            w2[0]=c.x; w2[1]=c.y; w2[2]=c.z; w2[3]=c.w;
            w3[0]=d.x; w3[1]=d.y; w3[2]=d.z; w3[3]=d.w;
        } else {
            #pragma unroll
            for (int h = 0; h < H; ++h) {
                w0[h] = wbuf[(size_t)i * H + h];
                w1[h] = wbuf[(size_t)(i + 1) * H + h];
                w2[h] = wbuf[(size_t)(i + 2) * H + h];
                w3[h] = wbuf[(size_t)(i + 3) * H + h];
            }
        }
        float v0[H], v1[H], v2[H], v3[H];
        #pragma unroll
        for (int h = 0; h < H; ++h) { v0[h] = r0[h * 64]; v1[h] = r1[h * 64];
                                      v2[h] = r2[h * 64]; v3[h] = r3[h * 64]; }
        #pragma unroll
        for (int h = 0; h < H; ++h) {
            acc0[h] += w0[h] * v0[h] + w2[h] * v2[h];
            acc1[h] += w1[h] * v1[h] + w3[h] * v3[h];
        }
    }
    for (; i < end; ++i) {
        int s = csr[i];
        const float* r = hbuf + (size_t)s * (H * 64) + lane;
        #pragma unroll
        for (int h = 0; h < H; ++h) acc0[h] += wbuf[(size_t)i * H + h] * r[h * 64];
    }

    if (!MEAN) {
        #pragma unroll
        for (int h = 0; h < H; ++h) {
            float val = (acc0[h] + acc1[h]) * rden[wid * H + h] + bias[h * 64 + lane];
            val = val > 0.f ? val : expm1f(val);   // ELU
            size_t idx = (size_t)wid * (H * 64) + h * 64 + lane;
            ushort_t hb = f2bf_bits(val);
            ohi[idx] = hb;
            olo[idx] = f2bf_bits(val - bfbits2f(hb));
        }
    } else {
        float m = 0.f;
        #pragma unroll
        for (int h = 0; h < H; ++h) m += (acc0[h] + acc1[h]) * rden[wid * H + h];
        outf[(size_t)wid * 64 + lane] = m * (1.f / (float)H) + bias[lane];
    }
}

// ============================ launch ========================================
extern "C" void kernel_launch(void* const* d_in, const int* in_sizes, int n_in,
                              void* d_out, int out_size, void* d_ws, size_t ws_size,
                              hipStream_t stream) {
    const float* x     = (const float*)d_in[0];
    const int*   ei    = (const int*)d_in[1];
    const float* W1    = (const float*)d_in[2];
    const float* a1s   = (const float*)d_in[3];
    const float* a1d   = (const float*)d_in[4];
    const float* b1    = (const float*)d_in[5];
    const float* W2    = (const float*)d_in[6];
    const float* a2s   = (const float*)d_in[7];
    const float* a2d   = (const float*)d_in[8];
    const float* b2    = (const float*)d_in[9];
    const float* W3    = (const float*)d_in[10];
    const float* a3s   = (const float*)d_in[11];
    const float* a3d   = (const float*)d_in[12];
    const float* b3    = (const float*)d_in[13];
    float* out = (float*)d_out;

    const int Nn = NNODES;
    const int E  = in_sizes[1] / 2;
    const int Etot = E + Nn;

    char* p = (char*)d_ws;
    auto carve = [&](size_t bytes) {
        char* r = p;
        p += (bytes + 255) & ~(size_t)255;
        return (void*)r;
    };
    float*    h_buf = (float*)carve((size_t)Nn * 384 * 4);
    ushort_t* R1    = (ushort_t*)carve((size_t)Nn * 256 * 4);   // hi/lo activation region
    ushort_t* x_hi  = R1;
    ushort_t* x_lo  = R1 + (size_t)Nn * 128;
    ushort_t* x1_hi = R1;                       // overlays x_hi/x_lo (dead by then)
    ushort_t* x1_lo = R1 + (size_t)Nn * 256;
    ushort_t* w1hi  = (ushort_t*)carve((size_t)128 * 256 * 2);
    ushort_t* w1lo  = (ushort_t*)carve((size_t)128 * 256 * 2);
    ushort_t* w2hi  = (ushort_t*)carve((size_t)256 * 256 * 2);
    ushort_t* w2lo  = (ushort_t*)carve((size_t)256 * 256 * 2);
    ushort_t* w3hi  = (ushort_t*)carve((size_t)256 * 384 * 2);
    ushort_t* w3lo  = (ushort_t*)carve((size_t)256 * 384 * 2);
    float* ssrc   = (float*)carve((size_t)Nn * 6 * 4);
    float* sdst   = (float*)carve((size_t)Nn * 6 * 4);
    float* rden   = (float*)carve((size_t)Nn * 6 * 4);
    float* wbuf   = (float*)carve((size_t)Etot * 6 * 4);
    int*   deg    = (int*)carve((size_t)Nn * 4);
    int*   offs   = (int*)carve((size_t)(Nn + 1) * 4);
    int*   cursor = (int*)carve((size_t)Nn * 4);
    int*   csr    = (int*)carve((size_t)Etot * 4);

    // -------- CSR build --------
    hipMemsetAsync(deg, 0, (size_t)Nn * 4, stream);
    {
        int nb = (Etot + 255) / 256;
        deg_kernel<<<nb, 256, 0, stream>>>(ei, E, Nn, deg);
        scan_kernel<<<1, 1024, 0, stream>>>(deg, offs, Nn);
        copy_int_kernel<<<(Nn + 255) / 256, 256, 0, stream>>>(offs, cursor, Nn);
        scatter_kernel<<<nb, 256, 0, stream>>>(ei, E, Nn, cursor, csr);
    }

    // -------- weight + input prep --------
    {
        int n4 = Nn * 128 / 4;
        split_kernel<<<(n4 + 255) / 256, 256, 0, stream>>>(
            (const float4*)x, (ushort4*)x_hi, (ushort4*)x_lo, n4);
        wprep_kernel<<<(128 * 256 + 255) / 256, 256, 0, stream>>>(W1, w1hi, w1lo, 128, 256);
        wprep_kernel<<<(256 * 256 + 255) / 256, 256, 0, stream>>>(W2, w2hi, w2lo, 256, 256);
        wprep_kernel<<<(256 * 384 + 255) / 256, 256, 0, stream>>>(W3, w3hi, w3lo, 256, 384);
    }

    const int node_blocks = (Nn + 3) / 4;

    // -------- layer 1: [50000,128] @ [128,256], H=4, concat+ELU --------
    {
        dim3 g(256 / 64, (Nn + 127) / 128);
        gemm_split_bf16<<<g, 256, 0, stream>>>(x_hi, x_lo, w1hi, w1lo, h_buf, Nn, 128, 256);
        score_kernel<4><<<node_blocks, 256, 0, stream>>>(h_buf, a1s, a1d, ssrc, sdst, Nn);
        smw_kernel<4><<<node_blocks, 256, 0, stream>>>(ssrc, sdst, offs, csr, wbuf, rden, Nn);
        agg_kernel<4, false><<<node_blocks, 256, 0, stream>>>(h_buf, wbuf, rden, offs, csr, b1,
                                                              nullptr, x1_hi, x1_lo, Nn);
    }
    // -------- layer 2: [50000,256] @ [256,256], H=4, concat+ELU --------
    {
        dim3 g(256 / 64, (Nn + 127) / 128);
        gemm_split_bf16<<<g, 256, 0, stream>>>(x1_hi, x1_lo, w2hi, w2lo, h_buf, Nn, 256, 256);
        score_kernel<4><<<node_blocks, 256, 0, stream>>>(h_buf, a2s, a2d, ssrc, sdst, Nn);
        smw_kernel<4><<<node_blocks, 256, 0, stream>>>(ssrc, sdst, offs, csr, wbuf, rden, Nn);
        agg_kernel<4, false><<<node_blocks, 256, 0, stream>>>(h_buf, wbuf, rden, offs, csr, b2,
                                                              nullptr, x1_hi, x1_lo, Nn);
    }
    // -------- layer 3: [50000,256] @ [256,384], H=6, mean --------
    {
        dim3 g(384 / 64, (Nn + 127) / 128);
        gemm_split_bf16<<<g, 256, 0, stream>>>(x1_hi, x1_lo, w3hi, w3lo, h_buf, Nn, 256, 384);
        score_kernel<6><<<node_blocks, 256, 0, stream>>>(h_buf, a3s, a3d, ssrc, sdst, Nn);
        smw_kernel<6><<<node_blocks, 256, 0, stream>>>(ssrc, sdst, offs, csr, wbuf, rden, Nn);
        agg_kernel<6, true><<<node_blocks, 256, 0, stream>>>(h_buf, wbuf, rden, offs, csr, b3,
                                                             out, nullptr, nullptr, Nn);
    }
}

// Round 4
// 911.487 us; speedup vs baseline: 2.0265x; 1.0766x over previous
//
#include <hip/hip_runtime.h>
#include <hip/hip_bf16.h>
#include <hip/hip_fp16.h>
#include <math.h>

#define NNODES 50000

typedef __attribute__((ext_vector_type(8))) short short8v;
typedef __attribute__((ext_vector_type(4))) float f32x4;
typedef unsigned short ushort_t;
typedef unsigned int uint_t;

// ---------------- bf16 / fp16 helpers ----------------
__device__ inline ushort_t f2bf_bits(float v) {
    union { __hip_bfloat16 b; ushort_t u; } c;
    c.b = __float2bfloat16(v);
    return c.u;
}
__device__ inline float bfbits2f(ushort_t u) {
    union { __hip_bfloat16 b; ushort_t u; } c;
    c.u = u;
    return __bfloat162float(c.b);
}
__device__ inline ushort_t f2h_bits(float v) {
    union { __half h; ushort_t u; } c;
    c.h = __float2half(v);
    return c.u;
}
__device__ inline void cvt2(uint_t u, float& a, float& b) {
    union { uint_t u; __half2 h; } c; c.u = u;
    a = __low2float(c.h); b = __high2float(c.h);
}

// split fp32 -> (hi, lo) bf16 pair, vectorized x4
__global__ __launch_bounds__(256)
void split_kernel(const float4* __restrict__ in, ushort4* __restrict__ hi,
                  ushort4* __restrict__ lo, int n4) {
    int i = blockIdx.x * blockDim.x + threadIdx.x;
    if (i >= n4) return;
    float4 v = in[i];
    ushort4 h, l;
    h.x = f2bf_bits(v.x); l.x = f2bf_bits(v.x - bfbits2f(h.x));
    h.y = f2bf_bits(v.y); l.y = f2bf_bits(v.y - bfbits2f(h.y));
    h.z = f2bf_bits(v.z); l.z = f2bf_bits(v.z - bfbits2f(h.z));
    h.w = f2bf_bits(v.w); l.w = f2bf_bits(v.w - bfbits2f(h.w));
    hi[i] = h; lo[i] = l;
}

// W [K][N] fp32 -> WT_hi/WT_lo [N][K] bf16
__global__ __launch_bounds__(256)
void wprep_kernel(const float* __restrict__ W, ushort_t* __restrict__ hiT,
                  ushort_t* __restrict__ loT, int K, int N) {
    int idx = blockIdx.x * blockDim.x + threadIdx.x;
    if (idx >= K * N) return;
    int k = idx / N, n = idx - k * N;
    float v = W[idx];
    ushort_t hb = f2bf_bits(v);
    hiT[(size_t)n * K + k] = hb;
    loT[(size_t)n * K + k] = f2bf_bits(v - bfbits2f(hb));
}

// ================= split-bf16 3-pass MFMA GEMM =================
// C[M][N] = A[M][K]*B[K][N]; A hi/lo bf16 [M][K], B hi/lo bf16 transposed [N][K].
// Also emits h16: fp16 copy in channel-major [n][c][heads] layout for agg gathers.
#define GTILE_LDA 40

__global__ __launch_bounds__(256)
void gemm_split_bf16(const ushort_t* __restrict__ Ahi, const ushort_t* __restrict__ Alo,
                     const ushort_t* __restrict__ Bhi, const ushort_t* __restrict__ Blo,
                     float* __restrict__ C, ushort_t* __restrict__ h16,
                     int M, int K, int N) {
    __shared__ short Ash_hi[128 * GTILE_LDA];
    __shared__ short Ash_lo[128 * GTILE_LDA];
    __shared__ short Bsh_hi[64 * GTILE_LDA];
    __shared__ short Bsh_lo[64 * GTILE_LDA];

    int tid = threadIdx.x;
    int lane = tid & 63;
    int wid = tid >> 6;
    int wm = wid >> 1, wn = wid & 1;
    int bm = blockIdx.y * 128;
    int bn = blockIdx.x * 64;
    int r15 = lane & 15;
    int kh = (lane >> 4) * 8;
    int heads = N >> 6;

    f32x4 acc[4][2] = {};

    for (int k0 = 0; k0 < K; k0 += 32) {
        #pragma unroll
        for (int j = 0; j < 2; ++j) {
            int c = tid + j * 256;
            int row = c >> 2;
            int kc = c & 3;
            int gr = bm + row;
            short8v vh = {}, vl = {};
            if (gr < M) {
                vh = *(const short8v*)&Ahi[(size_t)gr * K + k0 + kc * 8];
                vl = *(const short8v*)&Alo[(size_t)gr * K + k0 + kc * 8];
            }
            *(short8v*)&Ash_hi[row * GTILE_LDA + kc * 8] = vh;
            *(short8v*)&Ash_lo[row * GTILE_LDA + kc * 8] = vl;
        }
        {
            int row = tid >> 2;
            int kc = tid & 3;
            *(short8v*)&Bsh_hi[row * GTILE_LDA + kc * 8] =
                *(const short8v*)&Bhi[(size_t)(bn + row) * K + k0 + kc * 8];
            *(short8v*)&Bsh_lo[row * GTILE_LDA + kc * 8] =
                *(const short8v*)&Blo[(size_t)(bn + row) * K + k0 + kc * 8];
        }
        __syncthreads();

        short8v ah[4], al[4], bh[2], bl[2];
        #pragma unroll
        for (int mi = 0; mi < 4; ++mi) {
            int r = wm * 64 + mi * 16 + r15;
            ah[mi] = *(const short8v*)&Ash_hi[r * GTILE_LDA + kh];
            al[mi] = *(const short8v*)&Ash_lo[r * GTILE_LDA + kh];
        }
        #pragma unroll
        for (int nj = 0; nj < 2; ++nj) {
            int r = wn * 32 + nj * 16 + r15;
            bh[nj] = *(const short8v*)&Bsh_hi[r * GTILE_LDA + kh];
            bl[nj] = *(const short8v*)&Bsh_lo[r * GTILE_LDA + kh];
        }
        #pragma unroll
        for (int mi = 0; mi < 4; ++mi)
            #pragma unroll
            for (int nj = 0; nj < 2; ++nj) {
                acc[mi][nj] = __builtin_amdgcn_mfma_f32_16x16x32_bf16(ah[mi], bh[nj], acc[mi][nj], 0, 0, 0);
                acc[mi][nj] = __builtin_amdgcn_mfma_f32_16x16x32_bf16(ah[mi], bl[nj], acc[mi][nj], 0, 0, 0);
                acc[mi][nj] = __builtin_amdgcn_mfma_f32_16x16x32_bf16(al[mi], bh[nj], acc[mi][nj], 0, 0, 0);
            }
        __syncthreads();
    }

    // epilogue: C/D layout col=lane&15, row=(lane>>4)*4+reg
    #pragma unroll
    for (int mi = 0; mi < 4; ++mi) {
        #pragma unroll
        for (int r = 0; r < 4; ++r) {
            int grow = bm + wm * 64 + mi * 16 + (lane >> 4) * 4 + r;
            if (grow < M) {
                #pragma unroll
                for (int nj = 0; nj < 2; ++nj) {
                    int col = bn + wn * 32 + nj * 16 + r15;
                    float v = acc[mi][nj][r];
                    C[(size_t)grow * N + col] = v;
                    h16[((size_t)grow * 64 + (col & 63)) * heads + (col >> 6)] = f2h_bits(v);
                }
            }
        }
    }
}

// ============================ CSR build =====================================
__global__ void deg_kernel(const int* __restrict__ ei, int E, int Nn,
                           int* __restrict__ deg) {
    int e = blockIdx.x * blockDim.x + threadIdx.x;
    int tot = E + Nn;
    if (e >= tot) return;
    int d = (e < E) ? ei[E + e] : (e - E);
    atomicAdd(&deg[d], 1);
}

__global__ __launch_bounds__(1024)
void scan_kernel(const int* __restrict__ deg, int* __restrict__ offs, int n) {
    __shared__ int sh[1024];
    __shared__ int carry_sh;
    int t = threadIdx.x;
    if (t == 0) carry_sh = 0;
    __syncthreads();
    for (int base = 0; base < n; base += 1024) {
        int i = base + t;
        int v = (i < n) ? deg[i] : 0;
        sh[t] = v;
        __syncthreads();
        for (int off = 1; off < 1024; off <<= 1) {
            int add = (t >= off) ? sh[t - off] : 0;
            __syncthreads();
            sh[t] += add;
            __syncthreads();
        }
        int carry = carry_sh;
        if (i < n) offs[i + 1] = carry + sh[t];
        __syncthreads();
        if (t == 1023) carry_sh = carry + sh[1023];
        __syncthreads();
    }
    if (t == 0) offs[0] = 0;
}

__global__ void copy_int_kernel(const int* __restrict__ src, int* __restrict__ dst, int n) {
    int i = blockIdx.x * blockDim.x + threadIdx.x;
    if (i < n) dst[i] = src[i];
}

__global__ void scatter_kernel(const int* __restrict__ ei, int E, int Nn,
                               int* __restrict__ cursor, int* __restrict__ csr_src) {
    int e = blockIdx.x * blockDim.x + threadIdx.x;
    int tot = E + Nn;
    if (e >= tot) return;
    int s, d;
    if (e < E) { s = ei[e]; d = ei[E + e]; }
    else       { s = d = e - E; }
    int pos = atomicAdd(&cursor[d], 1);
    csr_src[pos] = s;
}

// ===================== per-node attention scores ============================
template<int H>
__global__ __launch_bounds__(256)
void score_kernel(const float* __restrict__ hbuf, const float* __restrict__ a_src,
                  const float* __restrict__ a_dst, float* __restrict__ s_src,
                  float* __restrict__ s_dst, int Nn) {
    int wid = (blockIdx.x * blockDim.x + threadIdx.x) >> 6;
    int lane = threadIdx.x & 63;
    if (wid >= Nn) return;
    const float* hrow = hbuf + (size_t)wid * (H * 64);
    #pragma unroll
    for (int h = 0; h < H; ++h) {
        float v = hrow[h * 64 + lane];
        float ps = v * a_src[h * 64 + lane];
        float pd = v * a_dst[h * 64 + lane];
        #pragma unroll
        for (int off = 32; off; off >>= 1) {
            ps += __shfl_xor(ps, off);
            pd += __shfl_xor(pd, off);
        }
        if (lane == 0) {
            s_src[wid * H + h] = ps;
            s_dst[wid * H + h] = pd;
        }
    }
}

// ---------------- vector load of ssrc row [H floats] ----------------
template<int H>
__device__ inline void loadS(const float* __restrict__ p, float* v) {
    if constexpr (H == 4) {
        float4 t = *(const float4*)p;
        v[0] = t.x; v[1] = t.y; v[2] = t.z; v[3] = t.w;
    } else {
        const float2* q = (const float2*)p;
        float2 a = q[0], b = q[1], c = q[2];
        v[0] = a.x; v[1] = a.y; v[2] = b.x; v[3] = b.y; v[4] = c.x; v[5] = c.y;
    }
}

// ============ score -> max -> edge weights + recip denominator ==============
template<int H>
__global__ __launch_bounds__(256)
void smw_kernel(const float* __restrict__ ssrc, const float* __restrict__ sdst,
                const int* __restrict__ offs, const int* __restrict__ csr,
                float* __restrict__ wbuf, float* __restrict__ rden, int Nn) {
    int wid = (blockIdx.x * blockDim.x + threadIdx.x) >> 6;
    int lane = threadIdx.x & 63;
    if (wid >= Nn) return;
    int beg = offs[wid], end = offs[wid + 1];
    float sd[H], mx[H], den[H];
    #pragma unroll
    for (int h = 0; h < H; ++h) {
        sd[h] = sdst[wid * H + h];
        mx[h] = -INFINITY;
        den[h] = 0.f;
    }
    for (int i = beg + lane; i < end; i += 64) {
        int s = csr[i];
        float sv[H];
        loadS<H>(ssrc + (size_t)s * H, sv);
        #pragma unroll
        for (int h = 0; h < H; ++h) mx[h] = fmaxf(mx[h], sv[h]);
    }
    #pragma unroll
    for (int h = 0; h < H; ++h) {
        #pragma unroll
        for (int off = 32; off; off >>= 1) mx[h] = fmaxf(mx[h], __shfl_xor(mx[h], off));
        float t = mx[h] + sd[h];
        mx[h] = t > 0.f ? t : 0.2f * t;
    }
    for (int i = beg + lane; i < end; i += 64) {
        int s = csr[i];
        float sv[H];
        loadS<H>(ssrc + (size_t)s * H, sv);
        #pragma unroll
        for (int h = 0; h < H; ++h) {
            float sc = sv[h] + sd[h];
            sc = sc > 0.f ? sc : 0.2f * sc;
            float w = __expf(sc - mx[h]);
            wbuf[(size_t)i * H + h] = w;
            den[h] += w;
        }
    }
    #pragma unroll
    for (int h = 0; h < H; ++h) {
        #pragma unroll
        for (int off = 32; off; off >>= 1) den[h] += __shfl_xor(den[h], off);
    }
    if (lane == 0) {
        #pragma unroll
        for (int h = 0; h < H; ++h) rden[wid * H + h] = 1.f / (den[h] + 1e-16f);
    }
}

// ---------------- packed fp16 gather helpers ----------------
template<int H> struct Packed;
template<> struct Packed<4> { uint_t a, b; };
template<> struct Packed<6> { uint_t a, b, c; };

template<int H>
__device__ inline Packed<H> load_p16(const ushort_t* __restrict__ p) {
    Packed<H> r;
    if constexpr (H == 4) {
        uint2 t = *(const uint2*)p;   // 8B aligned: (s*64+lane)*4 halves
        r.a = t.x; r.b = t.y;
    } else {
        const uint_t* q = (const uint_t*)p;  // 4B aligned only
        r.a = q[0]; r.b = q[1]; r.c = q[2];
    }
    return r;
}
template<int H>
__device__ inline void unpack_p16(const Packed<H>& g, float* v) {
    cvt2(g.a, v[0], v[1]);
    cvt2(g.b, v[2], v[3]);
    if constexpr (H == 6) cvt2(g.c, v[4], v[5]);
}

// ===================== weighted aggregation (fp16 gathers) ==================
// wave per node, lane = channel; one packed 8B/12B gather per edge per lane.
template<int H, bool MEAN>
__global__ __launch_bounds__(256)
void agg_kernel(const ushort_t* __restrict__ h16, const float* __restrict__ wbuf,
                const float* __restrict__ rden, const int* __restrict__ offs,
                const int* __restrict__ csr, const float* __restrict__ bias,
                float* __restrict__ outf, ushort_t* __restrict__ ohi,
                ushort_t* __restrict__ olo, int Nn) {
    int wid = (blockIdx.x * blockDim.x + threadIdx.x) >> 6;
    int lane = threadIdx.x & 63;
    if (wid >= Nn) return;
    int beg = offs[wid], end = offs[wid + 1];

    constexpr int U = (H == 4) ? 8 : 4;
    float acc0[H] = {}, acc1[H] = {};
    int i = beg;
    for (; i + U <= end; i += U) {
        int s[U];
        #pragma unroll
        for (int j = 0; j < U; ++j) s[j] = csr[i + j];
        float w[U][H];
        #pragma unroll
        for (int j = 0; j < U; ++j) {
            if constexpr (H == 4) {
                float4 t = *(const float4*)&wbuf[(size_t)(i + j) * 4];
                w[j][0] = t.x; w[j][1] = t.y; w[j][2] = t.z; w[j][3] = t.w;
            } else {
                const float2* q = (const float2*)&wbuf[(size_t)(i + j) * 6];
                float2 a = q[0], b = q[1], c = q[2];
                w[j][0] = a.x; w[j][1] = a.y; w[j][2] = b.x;
                w[j][3] = b.y; w[j][4] = c.x; w[j][5] = c.y;
            }
        }
        Packed<H> g[U];
        #pragma unroll
        for (int j = 0; j < U; ++j)
            g[j] = load_p16<H>(h16 + ((size_t)s[j] * 64 + lane) * H);
        #pragma unroll
        for (int j = 0; j < U; ++j) {
            float v[H];
            unpack_p16<H>(g[j], v);
            float* a = (j & 1) ? acc1 : acc0;
            #pragma unroll
            for (int h = 0; h < H; ++h) a[h] += w[j][h] * v[h];
        }
    }
    for (; i < end; ++i) {
        int s = csr[i];
        Packed<H> g = load_p16<H>(h16 + ((size_t)s * 64 + lane) * H);
        float v[H];
        unpack_p16<H>(g, v);
        #pragma unroll
        for (int h = 0; h < H; ++h) acc0[h] += wbuf[(size_t)i * H + h] * v[h];
    }

    if (!MEAN) {
        #pragma unroll
        for (int h = 0; h < H; ++h) {
            float val = (acc0[h] + acc1[h]) * rden[wid * H + h] + bias[h * 64 + lane];
            val = val > 0.f ? val : expm1f(val);   // ELU
            size_t idx = (size_t)wid * (H * 64) + h * 64 + lane;
            ushort_t hb = f2bf_bits(val);
            ohi[idx] = hb;
            olo[idx] = f2bf_bits(val - bfbits2f(hb));
        }
    } else {
        float m = 0.f;
        #pragma unroll
        for (int h = 0; h < H; ++h) m += (acc0[h] + acc1[h]) * rden[wid * H + h];
        outf[(size_t)wid * 64 + lane] = m * (1.f / (float)H) + bias[lane];
    }
}

// ============================ launch ========================================
extern "C" void kernel_launch(void* const* d_in, const int* in_sizes, int n_in,
                              void* d_out, int out_size, void* d_ws, size_t ws_size,
                              hipStream_t stream) {
    const float* x     = (const float*)d_in[0];
    const int*   ei    = (const int*)d_in[1];
    const float* W1    = (const float*)d_in[2];
    const float* a1s   = (const float*)d_in[3];
    const float* a1d   = (const float*)d_in[4];
    const float* b1    = (const float*)d_in[5];
    const float* W2    = (const float*)d_in[6];
    const float* a2s   = (const float*)d_in[7];
    const float* a2d   = (const float*)d_in[8];
    const float* b2    = (const float*)d_in[9];
    const float* W3    = (const float*)d_in[10];
    const float* a3s   = (const float*)d_in[11];
    const float* a3d   = (const float*)d_in[12];
    const float* b3    = (const float*)d_in[13];
    float* out = (float*)d_out;

    const int Nn = NNODES;
    const int E  = in_sizes[1] / 2;
    const int Etot = E + Nn;

    char* p = (char*)d_ws;
    auto carve = [&](size_t bytes) {
        char* r = p;
        p += (bytes + 255) & ~(size_t)255;
        return (void*)r;
    };
    float*    h_buf = (float*)carve((size_t)Nn * 384 * 4);
    ushort_t* h16   = (ushort_t*)carve((size_t)Nn * 384 * 2);
    ushort_t* R1    = (ushort_t*)carve((size_t)Nn * 256 * 4);
    ushort_t* x_hi  = R1;
    ushort_t* x_lo  = R1 + (size_t)Nn * 128;
    ushort_t* x1_hi = R1;
    ushort_t* x1_lo = R1 + (size_t)Nn * 256;
    ushort_t* w1hi  = (ushort_t*)carve((size_t)128 * 256 * 2);
    ushort_t* w1lo  = (ushort_t*)carve((size_t)128 * 256 * 2);
    ushort_t* w2hi  = (ushort_t*)carve((size_t)256 * 256 * 2);
    ushort_t* w2lo  = (ushort_t*)carve((size_t)256 * 256 * 2);
    ushort_t* w3hi  = (ushort_t*)carve((size_t)256 * 384 * 2);
    ushort_t* w3lo  = (ushort_t*)carve((size_t)256 * 384 * 2);
    float* ssrc   = (float*)carve((size_t)Nn * 6 * 4);
    float* sdst   = (float*)carve((size_t)Nn * 6 * 4);
    float* rden   = (float*)carve((size_t)Nn * 6 * 4);
    float* wbuf   = (float*)carve((size_t)Etot * 6 * 4);
    int*   deg    = (int*)carve((size_t)Nn * 4);
    int*   offs   = (int*)carve((size_t)(Nn + 1) * 4);
    int*   cursor = (int*)carve((size_t)Nn * 4);
    int*   csr    = (int*)carve((size_t)Etot * 4);

    // -------- CSR build --------
    hipMemsetAsync(deg, 0, (size_t)Nn * 4, stream);
    {
        int nb = (Etot + 255) / 256;
        deg_kernel<<<nb, 256, 0, stream>>>(ei, E, Nn, deg);
        scan_kernel<<<1, 1024, 0, stream>>>(deg, offs, Nn);
        copy_int_kernel<<<(Nn + 255) / 256, 256, 0, stream>>>(offs, cursor, Nn);
        scatter_kernel<<<nb, 256, 0, stream>>>(ei, E, Nn, cursor, csr);
    }

    // -------- weight + input prep --------
    {
        int n4 = Nn * 128 / 4;
        split_kernel<<<(n4 + 255) / 256, 256, 0, stream>>>(
            (const float4*)x, (ushort4*)x_hi, (ushort4*)x_lo, n4);
        wprep_kernel<<<(128 * 256 + 255) / 256, 256, 0, stream>>>(W1, w1hi, w1lo, 128, 256);
        wprep_kernel<<<(256 * 256 + 255) / 256, 256, 0, stream>>>(W2, w2hi, w2lo, 256, 256);
        wprep_kernel<<<(256 * 384 + 255) / 256, 256, 0, stream>>>(W3, w3hi, w3lo, 256, 384);
    }

    const int node_blocks = (Nn + 3) / 4;

    // -------- layer 1: [50000,128] @ [128,256], H=4, concat+ELU --------
    {
        dim3 g(256 / 64, (Nn + 127) / 128);
        gemm_split_bf16<<<g, 256, 0, stream>>>(x_hi, x_lo, w1hi, w1lo, h_buf, h16, Nn, 128, 256);
        score_kernel<4><<<node_blocks, 256, 0, stream>>>(h_buf, a1s, a1d, ssrc, sdst, Nn);
        smw_kernel<4><<<node_blocks, 256, 0, stream>>>(ssrc, sdst, offs, csr, wbuf, rden, Nn);
        agg_kernel<4, false><<<node_blocks, 256, 0, stream>>>(h16, wbuf, rden, offs, csr, b1,
                                                              nullptr, x1_hi, x1_lo, Nn);
    }
    // -------- layer 2: [50000,256] @ [256,256], H=4, concat+ELU --------
    {
        dim3 g(256 / 64, (Nn + 127) / 128);
        gemm_split_bf16<<<g, 256, 0, stream>>>(x1_hi, x1_lo, w2hi, w2lo, h_buf, h16, Nn, 256, 256);
        score_kernel<4><<<node_blocks, 256, 0, stream>>>(h_buf, a2s, a2d, ssrc, sdst, Nn);
        smw_kernel<4><<<node_blocks, 256, 0, stream>>>(ssrc, sdst, offs, csr, wbuf, rden, Nn);
        agg_kernel<4, false><<<node_blocks, 256, 0, stream>>>(h16, wbuf, rden, offs, csr, b2,
                                                              nullptr, x1_hi, x1_lo, Nn);
    }
    // -------- layer 3: [50000,256] @ [256,384], H=6, mean --------
    {
        dim3 g(384 / 64, (Nn + 127) / 128);
        gemm_split_bf16<<<g, 256, 0, stream>>>(x1_hi, x1_lo, w3hi, w3lo, h_buf, h16, Nn, 256, 384);
        score_kernel<6><<<node_blocks, 256, 0, stream>>>(h_buf, a3s, a3d, ssrc, sdst, Nn);
        smw_kernel<6><<<node_blocks, 256, 0, stream>>>(ssrc, sdst, offs, csr, wbuf, rden, Nn);
        agg_kernel<6, true><<<node_blocks, 256, 0, stream>>>(h16, wbuf, rden, offs, csr, b3,
                                                             out, nullptr, nullptr, Nn);
    }
}

// Round 5
// 865.223 us; speedup vs baseline: 2.1349x; 1.0535x over previous
//
#include <hip/hip_runtime.h>
#include <hip/hip_bf16.h>
#include <hip/hip_fp16.h>
#include <math.h>

#define NNODES 50000

typedef __attribute__((ext_vector_type(8))) short short8v;
typedef __attribute__((ext_vector_type(4))) float f32x4;
typedef unsigned short ushort_t;
typedef unsigned int uint_t;

// ---------------- bf16 / fp16 helpers ----------------
__device__ inline ushort_t f2bf_bits(float v) {
    union { __hip_bfloat16 b; ushort_t u; } c;
    c.b = __float2bfloat16(v);
    return c.u;
}
__device__ inline float bfbits2f(ushort_t u) {
    union { __hip_bfloat16 b; ushort_t u; } c;
    c.u = u;
    return __bfloat162float(c.b);
}
__device__ inline ushort_t f2h_bits(float v) {
    union { __half h; ushort_t u; } c;
    c.h = __float2half(v);
    return c.u;
}
__device__ inline void cvt2(uint_t u, float& a, float& b) {
    union { uint_t u; __half2 h; } c; c.u = u;
    a = __low2float(c.h); b = __high2float(c.h);
}

// split fp32 -> (hi, lo) bf16 pair, vectorized x4
__global__ __launch_bounds__(256)
void split_kernel(const float4* __restrict__ in, ushort4* __restrict__ hi,
                  ushort4* __restrict__ lo, int n4) {
    int i = blockIdx.x * blockDim.x + threadIdx.x;
    if (i >= n4) return;
    float4 v = in[i];
    ushort4 h, l;
    h.x = f2bf_bits(v.x); l.x = f2bf_bits(v.x - bfbits2f(h.x));
    h.y = f2bf_bits(v.y); l.y = f2bf_bits(v.y - bfbits2f(h.y));
    h.z = f2bf_bits(v.z); l.z = f2bf_bits(v.z - bfbits2f(h.z));
    h.w = f2bf_bits(v.w); l.w = f2bf_bits(v.w - bfbits2f(h.w));
    hi[i] = h; lo[i] = l;
}

// W [K][N] fp32 -> WT_hi/WT_lo [N][K] bf16
__global__ __launch_bounds__(256)
void wprep_kernel(const float* __restrict__ W, ushort_t* __restrict__ hiT,
                  ushort_t* __restrict__ loT, int K, int N) {
    int idx = blockIdx.x * blockDim.x + threadIdx.x;
    if (idx >= K * N) return;
    int k = idx / N, n = idx - k * N;
    float v = W[idx];
    ushort_t hb = f2bf_bits(v);
    hiT[(size_t)n * K + k] = hb;
    loT[(size_t)n * K + k] = f2bf_bits(v - bfbits2f(hb));
}

// ================= split-bf16 3-pass MFMA GEMM =================
// C[M][N] = A[M][K]*B[K][N]; A hi/lo bf16 [M][K], B hi/lo bf16 transposed [N][K].
#define GTILE_LDA 40

__global__ __launch_bounds__(256)
void gemm_split_bf16(const ushort_t* __restrict__ Ahi, const ushort_t* __restrict__ Alo,
                     const ushort_t* __restrict__ Bhi, const ushort_t* __restrict__ Blo,
                     float* __restrict__ C, int M, int K, int N) {
    __shared__ short Ash_hi[128 * GTILE_LDA];
    __shared__ short Ash_lo[128 * GTILE_LDA];
    __shared__ short Bsh_hi[64 * GTILE_LDA];
    __shared__ short Bsh_lo[64 * GTILE_LDA];

    int tid = threadIdx.x;
    int lane = tid & 63;
    int wid = tid >> 6;
    int wm = wid >> 1, wn = wid & 1;
    int bm = blockIdx.y * 128;
    int bn = blockIdx.x * 64;
    int r15 = lane & 15;
    int kh = (lane >> 4) * 8;

    f32x4 acc[4][2] = {};

    for (int k0 = 0; k0 < K; k0 += 32) {
        #pragma unroll
        for (int j = 0; j < 2; ++j) {
            int c = tid + j * 256;
            int row = c >> 2;
            int kc = c & 3;
            int gr = bm + row;
            short8v vh = {}, vl = {};
            if (gr < M) {
                vh = *(const short8v*)&Ahi[(size_t)gr * K + k0 + kc * 8];
                vl = *(const short8v*)&Alo[(size_t)gr * K + k0 + kc * 8];
            }
            *(short8v*)&Ash_hi[row * GTILE_LDA + kc * 8] = vh;
            *(short8v*)&Ash_lo[row * GTILE_LDA + kc * 8] = vl;
        }
        {
            int row = tid >> 2;
            int kc = tid & 3;
            *(short8v*)&Bsh_hi[row * GTILE_LDA + kc * 8] =
                *(const short8v*)&Bhi[(size_t)(bn + row) * K + k0 + kc * 8];
            *(short8v*)&Bsh_lo[row * GTILE_LDA + kc * 8] =
                *(const short8v*)&Blo[(size_t)(bn + row) * K + k0 + kc * 8];
        }
        __syncthreads();

        short8v ah[4], al[4], bh[2], bl[2];
        #pragma unroll
        for (int mi = 0; mi < 4; ++mi) {
            int r = wm * 64 + mi * 16 + r15;
            ah[mi] = *(const short8v*)&Ash_hi[r * GTILE_LDA + kh];
            al[mi] = *(const short8v*)&Ash_lo[r * GTILE_LDA + kh];
        }
        #pragma unroll
        for (int nj = 0; nj < 2; ++nj) {
            int r = wn * 32 + nj * 16 + r15;
            bh[nj] = *(const short8v*)&Bsh_hi[r * GTILE_LDA + kh];
            bl[nj] = *(const short8v*)&Bsh_lo[r * GTILE_LDA + kh];
        }
        #pragma unroll
        for (int mi = 0; mi < 4; ++mi)
            #pragma unroll
            for (int nj = 0; nj < 2; ++nj) {
                acc[mi][nj] = __builtin_amdgcn_mfma_f32_16x16x32_bf16(ah[mi], bh[nj], acc[mi][nj], 0, 0, 0);
                acc[mi][nj] = __builtin_amdgcn_mfma_f32_16x16x32_bf16(ah[mi], bl[nj], acc[mi][nj], 0, 0, 0);
                acc[mi][nj] = __builtin_amdgcn_mfma_f32_16x16x32_bf16(al[mi], bh[nj], acc[mi][nj], 0, 0, 0);
            }
        __syncthreads();
    }

    // epilogue: C/D layout col=lane&15, row=(lane>>4)*4+reg
    #pragma unroll
    for (int mi = 0; mi < 4; ++mi) {
        #pragma unroll
        for (int r = 0; r < 4; ++r) {
            int grow = bm + wm * 64 + mi * 16 + (lane >> 4) * 4 + r;
            if (grow < M) {
                #pragma unroll
                for (int nj = 0; nj < 2; ++nj)
                    C[(size_t)grow * N + bn + wn * 32 + nj * 16 + r15] = acc[mi][nj][r];
            }
        }
    }
}

// ============ pack h (fp32 [n][H*64]) -> h16 (fp16 [n][64][H]) ==============
// wave per node: lane = channel; coalesced reads and one 8B/12B store per lane.
template<int H>
__global__ __launch_bounds__(256)
void pack16_kernel(const float* __restrict__ hbuf, ushort_t* __restrict__ h16, int Nn) {
    int wid = (blockIdx.x * blockDim.x + threadIdx.x) >> 6;
    int lane = threadIdx.x & 63;
    if (wid >= Nn) return;
    const float* row = hbuf + (size_t)wid * (H * 64) + lane;
    uint_t u[H / 2];
    #pragma unroll
    for (int h = 0; h < H; h += 2) {
        uint_t lo = f2h_bits(row[h * 64]);
        uint_t hi = f2h_bits(row[(h + 1) * 64]);
        u[h / 2] = lo | (hi << 16);
    }
    ushort_t* dst = h16 + ((size_t)wid * 64 + lane) * H;
    if constexpr (H == 4) {
        uint2 t; t.x = u[0]; t.y = u[1];
        *(uint2*)dst = t;
    } else {
        uint_t* q = (uint_t*)dst;     // 12B stride -> only 4B alignment guaranteed
        q[0] = u[0]; q[1] = u[1]; q[2] = u[2];
    }
}

// ============================ CSR build =====================================
__global__ void deg_kernel(const int* __restrict__ ei, int E, int Nn,
                           int* __restrict__ deg) {
    int e = blockIdx.x * blockDim.x + threadIdx.x;
    int tot = E + Nn;
    if (e >= tot) return;
    int d = (e < E) ? ei[E + e] : (e - E);
    atomicAdd(&deg[d], 1);
}

__global__ __launch_bounds__(1024)
void scan_kernel(const int* __restrict__ deg, int* __restrict__ offs, int n) {
    __shared__ int sh[1024];
    __shared__ int carry_sh;
    int t = threadIdx.x;
    if (t == 0) carry_sh = 0;
    __syncthreads();
    for (int base = 0; base < n; base += 1024) {
        int i = base + t;
        int v = (i < n) ? deg[i] : 0;
        sh[t] = v;
        __syncthreads();
        for (int off = 1; off < 1024; off <<= 1) {
            int add = (t >= off) ? sh[t - off] : 0;
            __syncthreads();
            sh[t] += add;
            __syncthreads();
        }
        int carry = carry_sh;
        if (i < n) offs[i + 1] = carry + sh[t];
        __syncthreads();
        if (t == 1023) carry_sh = carry + sh[1023];
        __syncthreads();
    }
    if (t == 0) offs[0] = 0;
}

__global__ void copy_int_kernel(const int* __restrict__ src, int* __restrict__ dst, int n) {
    int i = blockIdx.x * blockDim.x + threadIdx.x;
    if (i < n) dst[i] = src[i];
}

__global__ void scatter_kernel(const int* __restrict__ ei, int E, int Nn,
                               int* __restrict__ cursor, int* __restrict__ csr_src) {
    int e = blockIdx.x * blockDim.x + threadIdx.x;
    int tot = E + Nn;
    if (e >= tot) return;
    int s, d;
    if (e < E) { s = ei[e]; d = ei[E + e]; }
    else       { s = d = e - E; }
    int pos = atomicAdd(&cursor[d], 1);
    csr_src[pos] = s;
}

// ===================== per-node attention scores ============================
template<int H>
__global__ __launch_bounds__(256)
void score_kernel(const float* __restrict__ hbuf, const float* __restrict__ a_src,
                  const float* __restrict__ a_dst, float* __restrict__ s_src,
                  float* __restrict__ s_dst, int Nn) {
    int wid = (blockIdx.x * blockDim.x + threadIdx.x) >> 6;
    int lane = threadIdx.x & 63;
    if (wid >= Nn) return;
    const float* hrow = hbuf + (size_t)wid * (H * 64);
    #pragma unroll
    for (int h = 0; h < H; ++h) {
        float v = hrow[h * 64 + lane];
        float ps = v * a_src[h * 64 + lane];
        float pd = v * a_dst[h * 64 + lane];
        #pragma unroll
        for (int off = 32; off; off >>= 1) {
            ps += __shfl_xor(ps, off);
            pd += __shfl_xor(pd, off);
        }
        if (lane == 0) {
            s_src[wid * H + h] = ps;
            s_dst[wid * H + h] = pd;
        }
    }
}

// ---------------- vector load of ssrc row [H floats] ----------------
template<int H>
__device__ inline void loadS(const float* __restrict__ p, float* v) {
    if constexpr (H == 4) {
        float4 t = *(const float4*)p;
        v[0] = t.x; v[1] = t.y; v[2] = t.z; v[3] = t.w;
    } else {
        const float2* q = (const float2*)p;
        float2 a = q[0], b = q[1], c = q[2];
        v[0] = a.x; v[1] = a.y; v[2] = b.x; v[3] = b.y; v[4] = c.x; v[5] = c.y;
    }
}

// ============ score -> max -> edge weights + recip denominator ==============
template<int H>
__global__ __launch_bounds__(256)
void smw_kernel(const float* __restrict__ ssrc, const float* __restrict__ sdst,
                const int* __restrict__ offs, const int* __restrict__ csr,
                float* __restrict__ wbuf, float* __restrict__ rden, int Nn) {
    int wid = (blockIdx.x * blockDim.x + threadIdx.x) >> 6;
    int lane = threadIdx.x & 63;
    if (wid >= Nn) return;
    int beg = offs[wid], end = offs[wid + 1];
    float sd[H], mx[H], den[H];
    #pragma unroll
    for (int h = 0; h < H; ++h) {
        sd[h] = sdst[wid * H + h];
        mx[h] = -INFINITY;
        den[h] = 0.f;
    }
    for (int i = beg + lane; i < end; i += 64) {
        int s = csr[i];
        float sv[H];
        loadS<H>(ssrc + (size_t)s * H, sv);
        #pragma unroll
        for (int h = 0; h < H; ++h) mx[h] = fmaxf(mx[h], sv[h]);
    }
    #pragma unroll
    for (int h = 0; h < H; ++h) {
        #pragma unroll
        for (int off = 32; off; off >>= 1) mx[h] = fmaxf(mx[h], __shfl_xor(mx[h], off));
        float t = mx[h] + sd[h];
        mx[h] = t > 0.f ? t : 0.2f * t;
    }
    for (int i = beg + lane; i < end; i += 64) {
        int s = csr[i];
        float sv[H];
        loadS<H>(ssrc + (size_t)s * H, sv);
        #pragma unroll
        for (int h = 0; h < H; ++h) {
            float sc = sv[h] + sd[h];
            sc = sc > 0.f ? sc : 0.2f * sc;
            float w = __expf(sc - mx[h]);
            wbuf[(size_t)i * H + h] = w;
            den[h] += w;
        }
    }
    #pragma unroll
    for (int h = 0; h < H; ++h) {
        #pragma unroll
        for (int off = 32; off; off >>= 1) den[h] += __shfl_xor(den[h], off);
    }
    if (lane == 0) {
        #pragma unroll
        for (int h = 0; h < H; ++h) rden[wid * H + h] = 1.f / (den[h] + 1e-16f);
    }
}

// ---------------- packed fp16 gather helpers ----------------
template<int H> struct Packed;
template<> struct Packed<4> { uint_t a, b; };
template<> struct Packed<6> { uint_t a, b, c; };

template<int H>
__device__ inline Packed<H> load_p16(const ushort_t* __restrict__ p) {
    Packed<H> r;
    if constexpr (H == 4) {
        uint2 t = *(const uint2*)p;
        r.a = t.x; r.b = t.y;
    } else {
        const uint_t* q = (const uint_t*)p;
        r.a = q[0]; r.b = q[1]; r.c = q[2];
    }
    return r;
}
template<int H>
__device__ inline void unpack_p16(const Packed<H>& g, float* v) {
    cvt2(g.a, v[0], v[1]);
    cvt2(g.b, v[2], v[3]);
    if constexpr (H == 6) cvt2(g.c, v[4], v[5]);
}

// ===================== weighted aggregation (fp16 gathers) ==================
template<int H, bool MEAN>
__global__ __launch_bounds__(256)
void agg_kernel(const ushort_t* __restrict__ h16, const float* __restrict__ wbuf,
                const float* __restrict__ rden, const int* __restrict__ offs,
                const int* __restrict__ csr, const float* __restrict__ bias,
                float* __restrict__ outf, ushort_t* __restrict__ ohi,
                ushort_t* __restrict__ olo, int Nn) {
    int wid = (blockIdx.x * blockDim.x + threadIdx.x) >> 6;
    int lane = threadIdx.x & 63;
    if (wid >= Nn) return;
    int beg = offs[wid], end = offs[wid + 1];

    constexpr int U = (H == 4) ? 8 : 4;
    float acc0[H] = {}, acc1[H] = {};
    int i = beg;
    for (; i + U <= end; i += U) {
        int s[U];
        #pragma unroll
        for (int j = 0; j < U; ++j) s[j] = csr[i + j];
        float w[U][H];
        #pragma unroll
        for (int j = 0; j < U; ++j) {
            if constexpr (H == 4) {
                float4 t = *(const float4*)&wbuf[(size_t)(i + j) * 4];
                w[j][0] = t.x; w[j][1] = t.y; w[j][2] = t.z; w[j][3] = t.w;
            } else {
                const float2* q = (const float2*)&wbuf[(size_t)(i + j) * 6];
                float2 a = q[0], b = q[1], c = q[2];
                w[j][0] = a.x; w[j][1] = a.y; w[j][2] = b.x;
                w[j][3] = b.y; w[j][4] = c.x; w[j][5] = c.y;
            }
        }
        Packed<H> g[U];
        #pragma unroll
        for (int j = 0; j < U; ++j)
            g[j] = load_p16<H>(h16 + ((size_t)s[j] * 64 + lane) * H);
        #pragma unroll
        for (int j = 0; j < U; ++j) {
            float v[H];
            unpack_p16<H>(g[j], v);
            float* a = (j & 1) ? acc1 : acc0;
            #pragma unroll
            for (int h = 0; h < H; ++h) a[h] += w[j][h] * v[h];
        }
    }
    for (; i < end; ++i) {
        int s = csr[i];
        Packed<H> g = load_p16<H>(h16 + ((size_t)s * 64 + lane) * H);
        float v[H];
        unpack_p16<H>(g, v);
        #pragma unroll
        for (int h = 0; h < H; ++h) acc0[h] += wbuf[(size_t)i * H + h] * v[h];
    }

    if (!MEAN) {
        #pragma unroll
        for (int h = 0; h < H; ++h) {
            float val = (acc0[h] + acc1[h]) * rden[wid * H + h] + bias[h * 64 + lane];
            val = val > 0.f ? val : expm1f(val);   // ELU
            size_t idx = (size_t)wid * (H * 64) + h * 64 + lane;
            ushort_t hb = f2bf_bits(val);
            ohi[idx] = hb;
            olo[idx] = f2bf_bits(val - bfbits2f(hb));
        }
    } else {
        float m = 0.f;
        #pragma unroll
        for (int h = 0; h < H; ++h) m += (acc0[h] + acc1[h]) * rden[wid * H + h];
        outf[(size_t)wid * 64 + lane] = m * (1.f / (float)H) + bias[lane];
    }
}

// ============================ launch ========================================
extern "C" void kernel_launch(void* const* d_in, const int* in_sizes, int n_in,
                              void* d_out, int out_size, void* d_ws, size_t ws_size,
                              hipStream_t stream) {
    const float* x     = (const float*)d_in[0];
    const int*   ei    = (const int*)d_in[1];
    const float* W1    = (const float*)d_in[2];
    const float* a1s   = (const float*)d_in[3];
    const float* a1d   = (const float*)d_in[4];
    const float* b1    = (const float*)d_in[5];
    const float* W2    = (const float*)d_in[6];
    const float* a2s   = (const float*)d_in[7];
    const float* a2d   = (const float*)d_in[8];
    const float* b2    = (const float*)d_in[9];
    const float* W3    = (const float*)d_in[10];
    const float* a3s   = (const float*)d_in[11];
    const float* a3d   = (const float*)d_in[12];
    const float* b3    = (const float*)d_in[13];
    float* out = (float*)d_out;

    const int Nn = NNODES;
    const int E  = in_sizes[1] / 2;
    const int Etot = E + Nn;

    char* p = (char*)d_ws;
    auto carve = [&](size_t bytes) {
        char* r = p;
        p += (bytes + 255) & ~(size_t)255;
        return (void*)r;
    };
    float*    h_buf = (float*)carve((size_t)Nn * 384 * 4);
    ushort_t* h16   = (ushort_t*)carve((size_t)Nn * 384 * 2);
    ushort_t* R1    = (ushort_t*)carve((size_t)Nn * 256 * 4);
    ushort_t* x_hi  = R1;
    ushort_t* x_lo  = R1 + (size_t)Nn * 128;
    ushort_t* x1_hi = R1;
    ushort_t* x1_lo = R1 + (size_t)Nn * 256;
    ushort_t* w1hi  = (ushort_t*)carve((size_t)128 * 256 * 2);
    ushort_t* w1lo  = (ushort_t*)carve((size_t)128 * 256 * 2);
    ushort_t* w2hi  = (ushort_t*)carve((size_t)256 * 256 * 2);
    ushort_t* w2lo  = (ushort_t*)carve((size_t)256 * 256 * 2);
    ushort_t* w3hi  = (ushort_t*)carve((size_t)256 * 384 * 2);
    ushort_t* w3lo  = (ushort_t*)carve((size_t)256 * 384 * 2);
    float* ssrc   = (float*)carve((size_t)Nn * 6 * 4);
    float* sdst   = (float*)carve((size_t)Nn * 6 * 4);
    float* rden   = (float*)carve((size_t)Nn * 6 * 4);
    float* wbuf   = (float*)carve((size_t)Etot * 6 * 4);
    int*   deg    = (int*)carve((size_t)Nn * 4);
    int*   offs   = (int*)carve((size_t)(Nn + 1) * 4);
    int*   cursor = (int*)carve((size_t)Nn * 4);
    int*   csr    = (int*)carve((size_t)Etot * 4);

    // -------- CSR build --------
    hipMemsetAsync(deg, 0, (size_t)Nn * 4, stream);
    {
        int nb = (Etot + 255) / 256;
        deg_kernel<<<nb, 256, 0, stream>>>(ei, E, Nn, deg);
        scan_kernel<<<1, 1024, 0, stream>>>(deg, offs, Nn);
        copy_int_kernel<<<(Nn + 255) / 256, 256, 0, stream>>>(offs, cursor, Nn);
        scatter_kernel<<<nb, 256, 0, stream>>>(ei, E, Nn, cursor, csr);
    }

    // -------- weight + input prep --------
    {
        int n4 = Nn * 128 / 4;
        split_kernel<<<(n4 + 255) / 256, 256, 0, stream>>>(
            (const float4*)x, (ushort4*)x_hi, (ushort4*)x_lo, n4);
        wprep_kernel<<<(128 * 256 + 255) / 256, 256, 0, stream>>>(W1, w1hi, w1lo, 128, 256);
        wprep_kernel<<<(256 * 256 + 255) / 256, 256, 0, stream>>>(W2, w2hi, w2lo, 256, 256);
        wprep_kernel<<<(256 * 384 + 255) / 256, 256, 0, stream>>>(W3, w3hi, w3lo, 256, 384);
    }

    const int node_blocks = (Nn + 3) / 4;

    // -------- layer 1: [50000,128] @ [128,256], H=4, concat+ELU --------
    {
        dim3 g(256 / 64, (Nn + 127) / 128);
        gemm_split_bf16<<<g, 256, 0, stream>>>(x_hi, x_lo, w1hi, w1lo, h_buf, Nn, 128, 256);
        pack16_kernel<4><<<node_blocks, 256, 0, stream>>>(h_buf, h16, Nn);
        score_kernel<4><<<node_blocks, 256, 0, stream>>>(h_buf, a1s, a1d, ssrc, sdst, Nn);
        smw_kernel<4><<<node_blocks, 256, 0, stream>>>(ssrc, sdst, offs, csr, wbuf, rden, Nn);
        agg_kernel<4, false><<<node_blocks, 256, 0, stream>>>(h16, wbuf, rden, offs, csr, b1,
                                                              nullptr, x1_hi, x1_lo, Nn);
    }
    // -------- layer 2: [50000,256] @ [256,256], H=4, concat+ELU --------
    {
        dim3 g(256 / 64, (Nn + 127) / 128);
        gemm_split_bf16<<<g, 256, 0, stream>>>(x1_hi, x1_lo, w2hi, w2lo, h_buf, Nn, 256, 256);
        pack16_kernel<4><<<node_blocks, 256, 0, stream>>>(h_buf, h16, Nn);
        score_kernel<4><<<node_blocks, 256, 0, stream>>>(h_buf, a2s, a2d, ssrc, sdst, Nn);
        smw_kernel<4><<<node_blocks, 256, 0, stream>>>(ssrc, sdst, offs, csr, wbuf, rden, Nn);
        agg_kernel<4, false><<<node_blocks, 256, 0, stream>>>(h16, wbuf, rden, offs, csr, b2,
                                                              nullptr, x1_hi, x1_lo, Nn);
    }
    // -------- layer 3: [50000,256] @ [256,384], H=6, mean --------
    {
        dim3 g(384 / 64, (Nn + 127) / 128);
        gemm_split_bf16<<<g, 256, 0, stream>>>(x1_hi, x1_lo, w3hi, w3lo, h_buf, Nn, 256, 384);
        pack16_kernel<6><<<node_blocks, 256, 0, stream>>>(h_buf, h16, Nn);
        score_kernel<6><<<node_blocks, 256, 0, stream>>>(h_buf, a3s, a3d, ssrc, sdst, Nn);
        smw_kernel<6><<<node_blocks, 256, 0, stream>>>(ssrc, sdst, offs, csr, wbuf, rden, Nn);
        agg_kernel<6, true><<<node_blocks, 256, 0, stream>>>(h16, wbuf, rden, offs, csr, b3,
                                                             out, nullptr, nullptr, Nn);
    }
}

// Round 6
// 676.513 us; speedup vs baseline: 2.7304x; 1.2789x over previous
//
#include <hip/hip_runtime.h>
#include <hip/hip_bf16.h>
#include <hip/hip_fp16.h>
#include <math.h>

#define NNODES 50000

typedef __attribute__((ext_vector_type(8))) short short8v;
typedef __attribute__((ext_vector_type(4))) float f32x4;
typedef unsigned short ushort_t;
typedef unsigned int uint_t;

// ---------------- bf16 / fp16 helpers ----------------
__device__ inline ushort_t f2bf_bits(float v) {
    union { __hip_bfloat16 b; ushort_t u; } c;
    c.b = __float2bfloat16(v);
    return c.u;
}
__device__ inline float bfbits2f(ushort_t u) {
    union { __hip_bfloat16 b; ushort_t u; } c;
    c.u = u;
    return __bfloat162float(c.b);
}
__device__ inline ushort_t f2h_bits(float v) {
    union { __half h; ushort_t u; } c;
    c.h = __float2half(v);
    return c.u;
}
__device__ inline void cvt2(uint_t u, float& a, float& b) {
    union { uint_t u; __half2 h; } c; c.u = u;
    a = __low2float(c.h); b = __high2float(c.h);
}

// split fp32 -> (hi, lo) bf16 pair, vectorized x4
__global__ __launch_bounds__(256)
void split_kernel(const float4* __restrict__ in, ushort4* __restrict__ hi,
                  ushort4* __restrict__ lo, int n4) {
    int i = blockIdx.x * blockDim.x + threadIdx.x;
    if (i >= n4) return;
    float4 v = in[i];
    ushort4 h, l;
    h.x = f2bf_bits(v.x); l.x = f2bf_bits(v.x - bfbits2f(h.x));
    h.y = f2bf_bits(v.y); l.y = f2bf_bits(v.y - bfbits2f(h.y));
    h.z = f2bf_bits(v.z); l.z = f2bf_bits(v.z - bfbits2f(h.z));
    h.w = f2bf_bits(v.w); l.w = f2bf_bits(v.w - bfbits2f(h.w));
    hi[i] = h; lo[i] = l;
}

// W [K][N] fp32 -> WT_hi/WT_lo [N][K] bf16
__global__ __launch_bounds__(256)
void wprep_kernel(const float* __restrict__ W, ushort_t* __restrict__ hiT,
                  ushort_t* __restrict__ loT, int K, int N) {
    int idx = blockIdx.x * blockDim.x + threadIdx.x;
    if (idx >= K * N) return;
    int k = idx / N, n = idx - k * N;
    float v = W[idx];
    ushort_t hb = f2bf_bits(v);
    hiT[(size_t)n * K + k] = hb;
    loT[(size_t)n * K + k] = f2bf_bits(v - bfbits2f(hb));
}

// ============ fused split-bf16 3-pass MFMA GEMM + pack + score ==============
// C = A[M][K] * B[K][N] (B stored transposed [N][K], hi/lo bf16).
// BM=128, BN=128 (exactly 2 heads), BK=32, 4 waves of 64x64.
// LDS staging is k-chunk-major: byte addr = chunk*2048 + row*16 -> conflict-free
// ds_read_b128 fragments (16 consecutive lanes read 256B contiguous).
// Epilogue: acc -> LDS fp16 (XOR-swizzled) -> head-pair plane h16[p][n][c][2]
// (dense 256B/node stores), plus fused s_src/s_dst dot-reduce.
template<int H>
__global__ __launch_bounds__(256)
void gemm_fused(const ushort_t* __restrict__ Ahi, const ushort_t* __restrict__ Alo,
                const ushort_t* __restrict__ Bhi, const ushort_t* __restrict__ Blo,
                ushort_t* __restrict__ h16, float* __restrict__ ssrc,
                float* __restrict__ sdst, const float* __restrict__ a_src,
                const float* __restrict__ a_dst, int M, int K) {
    __shared__ char smem[32768];            // staging (4x8KB) / epilogue h2 union
    __shared__ float sSs[128][2], sDs[128][2];

    const int tid = threadIdx.x;
    const int lane = tid & 63;
    const int wid = tid >> 6;
    const int wm = wid >> 1, wn = wid & 1;
    const int bm = blockIdx.y * 128;
    const int bn = blockIdx.x * 128;
    const int r15 = lane & 15;
    const int g4 = lane >> 4;

    if (tid < 128) { sSs[tid][0] = 0.f; sSs[tid][1] = 0.f;
                     sDs[tid][0] = 0.f; sDs[tid][1] = 0.f; }

    char* As_hi = smem;
    char* As_lo = smem + 8192;
    char* Bs_hi = smem + 16384;
    char* Bs_lo = smem + 24576;

    const int srow = tid >> 1;          // staging row 0..127
    const int sch  = (tid & 1) * 2;     // staging k-chunk base (0 or 2)
    const size_t arow = (size_t)(bm + srow) * K;
    const size_t brow = (size_t)(bn + srow) * K;

    f32x4 acc[4][4] = {};

    for (int k0 = 0; k0 < K; k0 += 32) {
        // issue global loads (rows >= M read adjacent ws buffers: safe, never stored)
        short8v a0 = *(const short8v*)&Ahi[arow + k0 + sch * 8];
        short8v a1 = *(const short8v*)&Ahi[arow + k0 + sch * 8 + 8];
        short8v l0 = *(const short8v*)&Alo[arow + k0 + sch * 8];
        short8v l1 = *(const short8v*)&Alo[arow + k0 + sch * 8 + 8];
        short8v b0 = *(const short8v*)&Bhi[brow + k0 + sch * 8];
        short8v b1 = *(const short8v*)&Bhi[brow + k0 + sch * 8 + 8];
        short8v m0 = *(const short8v*)&Blo[brow + k0 + sch * 8];
        short8v m1 = *(const short8v*)&Blo[brow + k0 + sch * 8 + 8];
        __syncthreads();                 // previous iteration's reads done
        *(short8v*)(As_hi + sch * 2048 + srow * 16)       = a0;
        *(short8v*)(As_hi + (sch + 1) * 2048 + srow * 16) = a1;
        *(short8v*)(As_lo + sch * 2048 + srow * 16)       = l0;
        *(short8v*)(As_lo + (sch + 1) * 2048 + srow * 16) = l1;
        *(short8v*)(Bs_hi + sch * 2048 + srow * 16)       = b0;
        *(short8v*)(Bs_hi + (sch + 1) * 2048 + srow * 16) = b1;
        *(short8v*)(Bs_lo + sch * 2048 + srow * 16)       = m0;
        *(short8v*)(Bs_lo + (sch + 1) * 2048 + srow * 16) = m1;
        __syncthreads();

        short8v ah[4], al[4], bh[4], bl[4];
        #pragma unroll
        for (int mi = 0; mi < 4; ++mi) {
            int row = wm * 64 + mi * 16 + r15;
            ah[mi] = *(const short8v*)(As_hi + g4 * 2048 + row * 16);
            al[mi] = *(const short8v*)(As_lo + g4 * 2048 + row * 16);
        }
        #pragma unroll
        for (int nj = 0; nj < 4; ++nj) {
            int row = wn * 64 + nj * 16 + r15;
            bh[nj] = *(const short8v*)(Bs_hi + g4 * 2048 + row * 16);
            bl[nj] = *(const short8v*)(Bs_lo + g4 * 2048 + row * 16);
        }
        #pragma unroll
        for (int mi = 0; mi < 4; ++mi)
            #pragma unroll
            for (int nj = 0; nj < 4; ++nj) {
                acc[mi][nj] = __builtin_amdgcn_mfma_f32_16x16x32_bf16(ah[mi], bh[nj], acc[mi][nj], 0, 0, 0);
                acc[mi][nj] = __builtin_amdgcn_mfma_f32_16x16x32_bf16(ah[mi], bl[nj], acc[mi][nj], 0, 0, 0);
                acc[mi][nj] = __builtin_amdgcn_mfma_f32_16x16x32_bf16(al[mi], bh[nj], acc[mi][nj], 0, 0, 0);
            }
    }
    __syncthreads();                    // all waves done reading staging LDS

    // ---- epilogue: h2 transpose + fused scores ----
    ushort_t* h2 = (ushort_t*)smem;     // [128 rows][128 cols] fp16, col XOR-swizzle
    const int headg = (bn >> 6) + wn;   // global head of this wave's 64-col slice
    float asv[4], adv[4];
    #pragma unroll
    for (int nj = 0; nj < 4; ++nj) {
        asv[nj] = a_src[headg * 64 + nj * 16 + r15];
        adv[nj] = a_dst[headg * 64 + nj * 16 + r15];
    }
    #pragma unroll
    for (int mi = 0; mi < 4; ++mi) {
        #pragma unroll
        for (int reg = 0; reg < 4; ++reg) {
            int row_l = wm * 64 + mi * 16 + g4 * 4 + reg;
            int csw = ((row_l >> 2) & 3) << 2;
            float pS = 0.f, pD = 0.f;
            #pragma unroll
            for (int nj = 0; nj < 4; ++nj) {
                float v = acc[mi][nj][reg];
                int col_l = wn * 64 + nj * 16 + r15;
                h2[row_l * 128 + (col_l ^ csw)] = f2h_bits(v);
                pS += v * asv[nj];
                pD += v * adv[nj];
            }
            #pragma unroll
            for (int off = 1; off < 16; off <<= 1) {   // reduce over the 16 r15 lanes
                pS += __shfl_xor(pS, off);
                pD += __shfl_xor(pD, off);
            }
            if (r15 == 0 && bm + row_l < M) {
                atomicAdd(&sSs[row_l][wn], pS);
                atomicAdd(&sDs[row_l][wn], pD);
            }
        }
    }
    __syncthreads();

    // h16 plane write: plane p = bn/128; per node 64 uint (=256B) contiguous
    uint_t* plane = (uint_t*)h16 + (size_t)(bn >> 7) * ((size_t)NNODES * 64);
    for (int u = tid; u < 128 * 64; u += 256) {
        int n_l = u >> 6, c = u & 63;
        if (bm + n_l < M) {
            int csw = ((n_l >> 2) & 3) << 2;
            uint_t lo = h2[n_l * 128 + (c ^ csw)];
            uint_t hi = h2[n_l * 128 + 64 + (c ^ csw)];
            plane[(size_t)(bm + n_l) * 64 + c] = lo | (hi << 16);
        }
    }
    // scores out
    {
        int row = tid >> 1, hl = tid & 1;
        if (bm + row < M) {
            int hg = (bn >> 6) + hl;
            ssrc[(size_t)(bm + row) * H + hg] = sSs[row][hl];
            sdst[(size_t)(bm + row) * H + hg] = sDs[row][hl];
        }
    }
}

// ============================ CSR build =====================================
__global__ void deg_kernel(const int* __restrict__ ei, int E, int Nn,
                           int* __restrict__ deg) {
    int e = blockIdx.x * blockDim.x + threadIdx.x;
    int tot = E + Nn;
    if (e >= tot) return;
    int d = (e < E) ? ei[E + e] : (e - E);
    atomicAdd(&deg[d], 1);
}

__global__ __launch_bounds__(1024)
void scan_kernel(const int* __restrict__ deg, int* __restrict__ offs, int n) {
    __shared__ int sh[1024];
    __shared__ int carry_sh;
    int t = threadIdx.x;
    if (t == 0) carry_sh = 0;
    __syncthreads();
    for (int base = 0; base < n; base += 1024) {
        int i = base + t;
        int v = (i < n) ? deg[i] : 0;
        sh[t] = v;
        __syncthreads();
        for (int off = 1; off < 1024; off <<= 1) {
            int add = (t >= off) ? sh[t - off] : 0;
            __syncthreads();
            sh[t] += add;
            __syncthreads();
        }
        int carry = carry_sh;
        if (i < n) offs[i + 1] = carry + sh[t];
        __syncthreads();
        if (t == 1023) carry_sh = carry + sh[1023];
        __syncthreads();
    }
    if (t == 0) offs[0] = 0;
}

__global__ void copy_int_kernel(const int* __restrict__ src, int* __restrict__ dst, int n) {
    int i = blockIdx.x * blockDim.x + threadIdx.x;
    if (i < n) dst[i] = src[i];
}

__global__ void scatter_kernel(const int* __restrict__ ei, int E, int Nn,
                               int* __restrict__ cursor, int* __restrict__ csr_src) {
    int e = blockIdx.x * blockDim.x + threadIdx.x;
    int tot = E + Nn;
    if (e >= tot) return;
    int s, d;
    if (e < E) { s = ei[e]; d = ei[E + e]; }
    else       { s = d = e - E; }
    int pos = atomicAdd(&cursor[d], 1);
    csr_src[pos] = s;
}

// ---------------- vector load of ssrc row [H floats] ----------------
template<int H>
__device__ inline void loadS(const float* __restrict__ p, float* v) {
    if constexpr (H == 4) {
        float4 t = *(const float4*)p;
        v[0] = t.x; v[1] = t.y; v[2] = t.z; v[3] = t.w;
    } else {
        const float2* q = (const float2*)p;
        float2 a = q[0], b = q[1], c = q[2];
        v[0] = a.x; v[1] = a.y; v[2] = b.x; v[3] = b.y; v[4] = c.x; v[5] = c.y;
    }
}

// ============ score -> max -> edge weights + recip denominator ==============
template<int H>
__global__ __launch_bounds__(256)
void smw_kernel(const float* __restrict__ ssrc, const float* __restrict__ sdst,
                const int* __restrict__ offs, const int* __restrict__ csr,
                float* __restrict__ wbuf, float* __restrict__ rden, int Nn) {
    int wid = (blockIdx.x * blockDim.x + threadIdx.x) >> 6;
    int lane = threadIdx.x & 63;
    if (wid >= Nn) return;
    int beg = offs[wid], end = offs[wid + 1];
    float sd[H], mx[H], den[H];
    #pragma unroll
    for (int h = 0; h < H; ++h) {
        sd[h] = sdst[wid * H + h];
        mx[h] = -INFINITY;
        den[h] = 0.f;
    }
    for (int i = beg + lane; i < end; i += 64) {
        int s = csr[i];
        float sv[H];
        loadS<H>(ssrc + (size_t)s * H, sv);
        #pragma unroll
        for (int h = 0; h < H; ++h) mx[h] = fmaxf(mx[h], sv[h]);
    }
    #pragma unroll
    for (int h = 0; h < H; ++h) {
        #pragma unroll
        for (int off = 32; off; off >>= 1) mx[h] = fmaxf(mx[h], __shfl_xor(mx[h], off));
        float t = mx[h] + sd[h];
        mx[h] = t > 0.f ? t : 0.2f * t;     // leaky is monotone
    }
    for (int i = beg + lane; i < end; i += 64) {
        int s = csr[i];
        float sv[H];
        loadS<H>(ssrc + (size_t)s * H, sv);
        #pragma unroll
        for (int h = 0; h < H; ++h) {
            float sc = sv[h] + sd[h];
            sc = sc > 0.f ? sc : 0.2f * sc;
            float w = __expf(sc - mx[h]);
            wbuf[(size_t)i * H + h] = w;
            den[h] += w;
        }
    }
    #pragma unroll
    for (int h = 0; h < H; ++h) {
        #pragma unroll
        for (int off = 32; off; off >>= 1) den[h] += __shfl_xor(den[h], off);
    }
    if (lane == 0) {
        #pragma unroll
        for (int h = 0; h < H; ++h) rden[wid * H + h] = 1.f / (den[h] + 1e-16f);
    }
}

// ===================== weighted aggregation (fp16 plane gathers) ============
// wave per node, lane = channel; H/2 uint gathers per edge per lane
// (plane p holds heads 2p, 2p+1 interleaved: dense 256B run per node per plane).
template<int H, bool MEAN>
__global__ __launch_bounds__(256)
void agg_kernel(const ushort_t* __restrict__ h16, const float* __restrict__ wbuf,
                const float* __restrict__ rden, const int* __restrict__ offs,
                const int* __restrict__ csr, const float* __restrict__ bias,
                float* __restrict__ outf, ushort_t* __restrict__ ohi,
                ushort_t* __restrict__ olo, int Nn) {
    constexpr int P = H / 2;
    int wid = (blockIdx.x * blockDim.x + threadIdx.x) >> 6;
    int lane = threadIdx.x & 63;
    if (wid >= Nn) return;
    int beg = offs[wid], end = offs[wid + 1];
    const uint_t* up = (const uint_t*)h16;
    const size_t psz = (size_t)Nn * 64;

    constexpr int U = (H == 4) ? 8 : 4;
    float acc0[H] = {}, acc1[H] = {};
    int i = beg;
    for (; i + U <= end; i += U) {
        int s[U];
        #pragma unroll
        for (int j = 0; j < U; ++j) s[j] = csr[i + j];
        uint_t g[U][P];
        #pragma unroll
        for (int j = 0; j < U; ++j)
            #pragma unroll
            for (int p = 0; p < P; ++p)
                g[j][p] = up[(size_t)p * psz + (size_t)s[j] * 64 + lane];
        float w[U][H];
        #pragma unroll
        for (int j = 0; j < U; ++j) {
            if constexpr (H == 4) {
                float4 t = *(const float4*)&wbuf[(size_t)(i + j) * 4];
                w[j][0] = t.x; w[j][1] = t.y; w[j][2] = t.z; w[j][3] = t.w;
            } else {
                const float2* q = (const float2*)&wbuf[(size_t)(i + j) * 6];
                float2 a = q[0], b = q[1], c = q[2];
                w[j][0] = a.x; w[j][1] = a.y; w[j][2] = b.x;
                w[j][3] = b.y; w[j][4] = c.x; w[j][5] = c.y;
            }
        }
        #pragma unroll
        for (int j = 0; j < U; ++j) {
            float v[H];
            #pragma unroll
            for (int p = 0; p < P; ++p) cvt2(g[j][p], v[2 * p], v[2 * p + 1]);
            float* a = (j & 1) ? acc1 : acc0;
            #pragma unroll
            for (int h = 0; h < H; ++h) a[h] += w[j][h] * v[h];
        }
    }
    for (; i < end; ++i) {
        int s = csr[i];
        float v[H];
        #pragma unroll
        for (int p = 0; p < P; ++p) {
            uint_t g = up[(size_t)p * psz + (size_t)s * 64 + lane];
            cvt2(g, v[2 * p], v[2 * p + 1]);
        }
        #pragma unroll
        for (int h = 0; h < H; ++h) acc0[h] += wbuf[(size_t)i * H + h] * v[h];
    }

    if (!MEAN) {
        #pragma unroll
        for (int h = 0; h < H; ++h) {
            float val = (acc0[h] + acc1[h]) * rden[wid * H + h] + bias[h * 64 + lane];
            val = val > 0.f ? val : expm1f(val);   // ELU
            size_t idx = (size_t)wid * (H * 64) + h * 64 + lane;
            ushort_t hb = f2bf_bits(val);
            ohi[idx] = hb;
            olo[idx] = f2bf_bits(val - bfbits2f(hb));
        }
    } else {
        float m = 0.f;
        #pragma unroll
        for (int h = 0; h < H; ++h) m += (acc0[h] + acc1[h]) * rden[wid * H + h];
        outf[(size_t)wid * 64 + lane] = m * (1.f / (float)H) + bias[lane];
    }
}

// ============================ launch ========================================
extern "C" void kernel_launch(void* const* d_in, const int* in_sizes, int n_in,
                              void* d_out, int out_size, void* d_ws, size_t ws_size,
                              hipStream_t stream) {
    const float* x     = (const float*)d_in[0];
    const int*   ei    = (const int*)d_in[1];
    const float* W1    = (const float*)d_in[2];
    const float* a1s   = (const float*)d_in[3];
    const float* a1d   = (const float*)d_in[4];
    const float* b1    = (const float*)d_in[5];
    const float* W2    = (const float*)d_in[6];
    const float* a2s   = (const float*)d_in[7];
    const float* a2d   = (const float*)d_in[8];
    const float* b2    = (const float*)d_in[9];
    const float* W3    = (const float*)d_in[10];
    const float* a3s   = (const float*)d_in[11];
    const float* a3d   = (const float*)d_in[12];
    const float* b3    = (const float*)d_in[13];
    float* out = (float*)d_out;

    const int Nn = NNODES;
    const int E  = in_sizes[1] / 2;
    const int Etot = E + Nn;

    char* p = (char*)d_ws;
    auto carve = [&](size_t bytes) {
        char* r = p;
        p += (bytes + 255) & ~(size_t)255;
        return (void*)r;
    };
    ushort_t* h16   = (ushort_t*)carve((size_t)Nn * 384 * 2);   // up to 3 planes
    ushort_t* R1    = (ushort_t*)carve((size_t)Nn * 256 * 4);
    ushort_t* x_hi  = R1;
    ushort_t* x_lo  = R1 + (size_t)Nn * 128;
    ushort_t* x1_hi = R1;
    ushort_t* x1_lo = R1 + (size_t)Nn * 256;
    ushort_t* w1hi  = (ushort_t*)carve((size_t)128 * 256 * 2);
    ushort_t* w1lo  = (ushort_t*)carve((size_t)128 * 256 * 2);
    ushort_t* w2hi  = (ushort_t*)carve((size_t)256 * 256 * 2);
    ushort_t* w2lo  = (ushort_t*)carve((size_t)256 * 256 * 2);
    ushort_t* w3hi  = (ushort_t*)carve((size_t)256 * 384 * 2);
    ushort_t* w3lo  = (ushort_t*)carve((size_t)256 * 384 * 2);
    float* ssrc   = (float*)carve((size_t)Nn * 6 * 4);
    float* sdst   = (float*)carve((size_t)Nn * 6 * 4);
    float* rden   = (float*)carve((size_t)Nn * 6 * 4);
    float* wbuf   = (float*)carve((size_t)Etot * 6 * 4);
    int*   deg    = (int*)carve((size_t)Nn * 4);
    int*   offs   = (int*)carve((size_t)(Nn + 1) * 4);
    int*   cursor = (int*)carve((size_t)Nn * 4);
    int*   csr    = (int*)carve((size_t)Etot * 4);

    // -------- CSR build --------
    hipMemsetAsync(deg, 0, (size_t)Nn * 4, stream);
    {
        int nb = (Etot + 255) / 256;
        deg_kernel<<<nb, 256, 0, stream>>>(ei, E, Nn, deg);
        scan_kernel<<<1, 1024, 0, stream>>>(deg, offs, Nn);
        copy_int_kernel<<<(Nn + 255) / 256, 256, 0, stream>>>(offs, cursor, Nn);
        scatter_kernel<<<nb, 256, 0, stream>>>(ei, E, Nn, cursor, csr);
    }

    // -------- weight + input prep --------
    {
        int n4 = Nn * 128 / 4;
        split_kernel<<<(n4 + 255) / 256, 256, 0, stream>>>(
            (const float4*)x, (ushort4*)x_hi, (ushort4*)x_lo, n4);
        wprep_kernel<<<(128 * 256 + 255) / 256, 256, 0, stream>>>(W1, w1hi, w1lo, 128, 256);
        wprep_kernel<<<(256 * 256 + 255) / 256, 256, 0, stream>>>(W2, w2hi, w2lo, 256, 256);
        wprep_kernel<<<(256 * 384 + 255) / 256, 256, 0, stream>>>(W3, w3hi, w3lo, 256, 384);
    }

    const int node_blocks = (Nn + 3) / 4;
    const int gemm_rows = (Nn + 127) / 128;

    // -------- layer 1: [50000,128] @ [128,256], H=4, concat+ELU --------
    {
        dim3 g(2, gemm_rows);
        gemm_fused<4><<<g, 256, 0, stream>>>(x_hi, x_lo, w1hi, w1lo, h16,
                                             ssrc, sdst, a1s, a1d, Nn, 128);
        smw_kernel<4><<<node_blocks, 256, 0, stream>>>(ssrc, sdst, offs, csr, wbuf, rden, Nn);
        agg_kernel<4, false><<<node_blocks, 256, 0, stream>>>(h16, wbuf, rden, offs, csr, b1,
                                                              nullptr, x1_hi, x1_lo, Nn);
    }
    // -------- layer 2: [50000,256] @ [256,256], H=4, concat+ELU --------
    {
        dim3 g(2, gemm_rows);
        gemm_fused<4><<<g, 256, 0, stream>>>(x1_hi, x1_lo, w2hi, w2lo, h16,
                                             ssrc, sdst, a2s, a2d, Nn, 256);
        smw_kernel<4><<<node_blocks, 256, 0, stream>>>(ssrc, sdst, offs, csr, wbuf, rden, Nn);
        agg_kernel<4, false><<<node_blocks, 256, 0, stream>>>(h16, wbuf, rden, offs, csr, b2,
                                                              nullptr, x1_hi, x1_lo, Nn);
    }
    // -------- layer 3: [50000,256] @ [256,384], H=6, mean --------
    {
        dim3 g(3, gemm_rows);
        gemm_fused<6><<<g, 256, 0, stream>>>(x1_hi, x1_lo, w3hi, w3lo, h16,
                                             ssrc, sdst, a3s, a3d, Nn, 256);
        smw_kernel<6><<<node_blocks, 256, 0, stream>>>(ssrc, sdst, offs, csr, wbuf, rden, Nn);
        agg_kernel<6, true><<<node_blocks, 256, 0, stream>>>(h16, wbuf, rden, offs, csr, b3,
                                                             out, nullptr, nullptr, Nn);
    }
}